// Round 18
// baseline (558.774 us; speedup 1.0000x reference)
//
#include <hip/hip_runtime.h>
#include <math.h>

#define H 32
#define N0 4096
#define EMAX 131072
#define APSTR (4096 * 32)

typedef __attribute__((ext_vector_type(4))) float floatx4;
typedef __attribute__((ext_vector_type(8))) short short8;

__device__ __forceinline__ unsigned short f2bf_bits(float v) {
    union { float f; unsigned u; } c;
    c.f = v;
    unsigned lsb = (c.u >> 16) & 1u;
    c.u += 0x7fffu + lsb;   // RNE; inputs here are small exact integers
    return (unsigned short)(c.u >> 16);
}

// ---------------- sentinel ----------------
__global__ void fill_sentinel_kernel(float* out, int n) {
    int t = blockIdx.x * 256 + threadIdx.x;
    if (t < n) out[t] = 9.0f;
}

// ---------------- CSR build ----------------
__global__ void build_stats_kernel(const int* __restrict__ ei, int E, int* __restrict__ rowcnt,
                                   int* __restrict__ rowcntD, int* __restrict__ diagcnt) {
    int t = blockIdx.x * 256 + threadIdx.x;
    if (t >= E) return;
    int s = ei[t], d = ei[E + t];
    if ((unsigned)s >= N0 || (unsigned)d >= N0) return;
    atomicAdd(&rowcnt[s], 1);
    atomicAdd(&rowcntD[d], 1);
    if (s == d) atomicAdd(&diagcnt[s], 1);
}

// both scans + cursor copies in one launch
__global__ __launch_bounds__(1024) void scan2_kernel(const int* __restrict__ cntA, int* __restrict__ rowpA,
                                                     int* __restrict__ curA, const int* __restrict__ cntB,
                                                     int* __restrict__ rowpB, int* __restrict__ curB) {
    __shared__ int part[1024];
    int tid = threadIdx.x;
    for (int pass = 0; pass < 2; pass++) {
        const int* cnt = pass ? cntB : cntA;
        int* rowp = pass ? rowpB : rowpA;
        int* cur = pass ? curB : curA;
        int base = tid * 4;
        int local[4];
        int s = 0;
#pragma unroll
        for (int i = 0; i < 4; i++) { local[i] = s; s += cnt[base + i]; }
        part[tid] = s;
        __syncthreads();
        for (int off = 1; off < 1024; off <<= 1) {
            int v = (tid >= off) ? part[tid - off] : 0;
            __syncthreads();
            part[tid] += v;
            __syncthreads();
        }
        int pre = (tid == 0) ? 0 : part[tid - 1];
#pragma unroll
        for (int i = 0; i < 4; i++) { rowp[base + i] = pre + local[i]; cur[base + i] = pre + local[i]; }
        if (tid == 1023) rowp[N0] = pre + s;
        __syncthreads();
    }
}

__global__ void fill_csr_kernel(const int* __restrict__ ei, int E, int* __restrict__ cursor,
                                int* __restrict__ cols, int* __restrict__ cursorD,
                                int* __restrict__ srcs) {
    int t = blockIdx.x * 256 + threadIdx.x;
    if (t >= E) return;
    int s = ei[t], d = ei[E + t];
    if ((unsigned)s >= N0 || (unsigned)d >= N0) return;
    int pos = atomicAdd(&cursor[s], 1);
    cols[pos] = d;
    int posD = atomicAdd(&cursorD[d], 1);
    srcs[posD] = s;
}

__global__ void invperm_set_kernel(const int* __restrict__ perm, int* __restrict__ invperm, int k) {
    int t = blockIdx.x * 256 + threadIdx.x;
    if (t < k) invperm[perm[t]] = t;
}

// ---------------- level-0 fused augment+pool ----------------
__global__ __launch_bounds__(256) void aug0_kernel(const int* __restrict__ rowp, const int* __restrict__ cols,
                                                   const int* __restrict__ perm, const int* __restrict__ invperm,
                                                   int kOut, int ldC, float* __restrict__ C) {
    __shared__ float row[2048];
    int a = blockIdx.x;
    int tid = threadIdx.x;
    for (int j = tid; j < ldC; j += 256) row[j] = 0.f;
    __syncthreads();
    if (a < kOut) {
        int pa = perm[a];
        int s0 = rowp[pa], s1 = rowp[pa + 1];
        for (int e = s0 + tid; e < s1; e += 256) {
            int k = cols[e];
            int ip = invperm[k];
            if (ip >= 0) atomicAdd(&row[ip], 2.0f);
            int t1 = rowp[k + 1];
            for (int e2 = rowp[k]; e2 < t1; ++e2) {
                int ip2 = invperm[cols[e2]];
                if (ip2 >= 0) atomicAdd(&row[ip2], 1.0f);
            }
        }
    }
    __syncthreads();
    for (int j = tid; j < ldC; j += 256) C[(long)a * ldC + j] = (j == a) ? 0.f : row[j];
}

// ---------------- deeper levels: pre-gathered operands + GEMM ----------------
__global__ void gather_rows_kernel(const float* __restrict__ M, int ldM, const int* __restrict__ perm,
                                   int kOut, float* __restrict__ Gr) {
    int k = blockIdx.x * 256 + threadIdx.x;
    int a = blockIdx.y;
    if (k >= ldM) return;
    float v = 0.f;
    if (a < kOut) {
        int pa = perm[a];
        v = M[(long)pa * ldM + k] + (k == pa ? 1.f : 0.f);
    }
    Gr[(long)a * ldM + k] = v;
}

__global__ void gather_rows_bf16_kernel(const float* __restrict__ M, int ldM, const int* __restrict__ perm,
                                        int kOut, unsigned short* __restrict__ Gr) {
    int k = blockIdx.x * 256 + threadIdx.x;
    int a = blockIdx.y;
    if (k >= ldM) return;
    float v = 0.f;
    if (a < kOut) {
        int pa = perm[a];
        v = M[(long)pa * ldM + k] + (k == pa ? 1.f : 0.f);
    }
    Gr[(long)a * ldM + k] = f2bf_bits(v);
}

__global__ void gather_cols_kernel(const float* __restrict__ M, int ldM, const int* __restrict__ perm,
                                   int kOut, float* __restrict__ Gc, int ldC) {
    int b = blockIdx.x * 256 + threadIdx.x;
    int k = blockIdx.y;
    if (b >= ldC) return;
    float v = 0.f;
    if (b < kOut) {
        int pb = perm[b];
        v = M[(long)k * ldM + pb] + (k == pb ? 1.f : 0.f);
    }
    Gc[(long)k * ldC + b] = v;
}

// fused gather+transpose+cvt: GcT[b][k] = bf16((M+I)[k, perm[b]]). Grid (ldn/32, ldM/32), block (32,8)
__global__ void gather_colsT_bf16_kernel(const float* __restrict__ M, int ldM,
                                         const int* __restrict__ perm, int kOut,
                                         unsigned short* __restrict__ GcT) {
    __shared__ float t[32][33];
    __shared__ int pb[32];
    int b0 = blockIdx.x * 32, k0 = blockIdx.y * 32;
    int tx = threadIdx.x, ty = threadIdx.y;
    if (ty == 0) pb[tx] = (b0 + tx < kOut) ? perm[b0 + tx] : -1;
    __syncthreads();
    for (int y = ty; y < 32; y += 8) {
        int k = k0 + y;
        int pbx = pb[tx];
        float v = 0.f;
        if (pbx >= 0) v = M[(long)k * ldM + pbx] + (k == pbx ? 1.f : 0.f);
        t[y][tx] = v;
    }
    __syncthreads();
    for (int y = ty; y < 32; y += 8)
        GcT[(long)(b0 + y) * ldM + k0 + tx] = f2bf_bits(t[tx][y]);
}

__global__ __launch_bounds__(256) void mfma_aug_kernel(const unsigned short* __restrict__ Aop,
                                                       const unsigned short* __restrict__ Bop,
                                                       float* __restrict__ C, int K, int ldC, int kchunk) {
    __shared__ __align__(16) unsigned short lA[64 * 32];
    __shared__ __align__(16) unsigned short lB[64 * 32];
    const int tid = threadIdx.x;
    const int lane = tid & 63;
    const int w = tid >> 6;
    const int a0 = blockIdx.y * 64, b0 = blockIdx.x * 64;
    const int kbase = blockIdx.z * kchunk;
    const int r0 = tid >> 2;
    const int c8 = (tid & 3) * 8;
    const unsigned short* gA = Aop + (long)(a0 + r0) * K + kbase + c8;
    const unsigned short* gB = Bop + (long)(b0 + r0) * K + kbase + c8;
    const int wm = (w & 1) * 32;
    const int wn = (w >> 1) * 32;
    const int lm = lane & 15;
    const int quad = lane >> 4;
    floatx4 acc[2][2];
#pragma unroll
    for (int i = 0; i < 2; i++)
#pragma unroll
        for (int j = 0; j < 2; j++) {
            floatx4 z = {0.f, 0.f, 0.f, 0.f};
            acc[i][j] = z;
        }
    for (int k0 = 0; k0 < kchunk; k0 += 32) {
        short8 va = *(const short8*)(gA + k0);
        short8 vb = *(const short8*)(gB + k0);
        __syncthreads();
        *(short8*)&lA[r0 * 32 + c8] = va;
        *(short8*)&lB[r0 * 32 + c8] = vb;
        __syncthreads();
        short8 af[2], bf[2];
#pragma unroll
        for (int mi = 0; mi < 2; mi++) af[mi] = *(const short8*)&lA[(wm + mi * 16 + lm) * 32 + quad * 8];
#pragma unroll
        for (int ni = 0; ni < 2; ni++) bf[ni] = *(const short8*)&lB[(wn + ni * 16 + lm) * 32 + quad * 8];
#pragma unroll
        for (int mi = 0; mi < 2; mi++)
#pragma unroll
            for (int ni = 0; ni < 2; ni++)
                acc[mi][ni] = __builtin_amdgcn_mfma_f32_16x16x32_bf16(af[mi], bf[ni], acc[mi][ni], 0, 0, 0);
    }
#pragma unroll
    for (int mi = 0; mi < 2; mi++)
#pragma unroll
        for (int ni = 0; ni < 2; ni++) {
            int col = b0 + wn + ni * 16 + lm;
#pragma unroll
            for (int r = 0; r < 4; r++) {
                int row = a0 + wm + mi * 16 + quad * 4 + r;
                if (row != col) atomicAdd(&C[(long)row * ldC + col], acc[mi][ni][r]);
            }
        }
}

__global__ __launch_bounds__(256) void gemm64_kernel(const float* __restrict__ Gr,
                                                     const float* __restrict__ Gc,
                                                     float* __restrict__ Cpart, int K, int ldC, int kchunk) {
    __shared__ float As[32][68];
    __shared__ float Bs[32][68];
    const int tid = threadIdx.x;
    const int a0 = blockIdx.y * 64, b0 = blockIdx.x * 64;
    const int kbase = blockIdx.z * kchunk;
    float* Cz = Cpart + (long)blockIdx.z * ldC * ldC;
    const int tx = tid & 15, ty = tid >> 4;
    const int lr = tid >> 2;
    const int lk = (tid & 3) * 8;
    const int bb = tid & 63;
    const int kr = (tid >> 6) * 8;
    const float* gA = Gr + (long)(a0 + lr) * K + lk + kbase;
    const float* gB = Gc + (long)(kr + kbase) * ldC + b0 + bb;
    float acc[4][4];
#pragma unroll
    for (int i = 0; i < 4; i++)
#pragma unroll
        for (int j = 0; j < 4; j++) acc[i][j] = 0.f;
    for (int k0 = 0; k0 < kchunk; k0 += 32) {
        float a8[8], b8[8];
#pragma unroll
        for (int i = 0; i < 8; i++) a8[i] = gA[k0 + i];
#pragma unroll
        for (int i = 0; i < 8; i++) b8[i] = gB[(long)(k0 + i) * ldC];
        __syncthreads();
#pragma unroll
        for (int i = 0; i < 8; i++) As[lk + i][lr] = a8[i];
#pragma unroll
        for (int i = 0; i < 8; i++) Bs[kr + i][bb] = b8[i];
        __syncthreads();
#pragma unroll
        for (int k = 0; k < 32; k++) {
            floatx4 av = *(const floatx4*)&As[k][ty * 4];
            floatx4 bv = *(const floatx4*)&Bs[k][tx * 4];
#pragma unroll
            for (int i = 0; i < 4; i++)
#pragma unroll
                for (int j = 0; j < 4; j++) acc[i][j] += av[i] * bv[j];
        }
    }
#pragma unroll
    for (int i = 0; i < 4; i++)
#pragma unroll
        for (int j = 0; j < 4; j++) {
            int a = a0 + ty * 4 + i, b = b0 + tx * 4 + j;
            Cz[(long)a * ldC + b] = acc[i][j];
        }
}

__global__ void reduce_part_kernel(const float* __restrict__ Cpart, float* __restrict__ C,
                                   int ldC, int ksplit) {
    int t = blockIdx.x * 256 + threadIdx.x;
    long tot = (long)ldC * ldC;
    if (t >= tot) return;
    float s = 0.f;
    for (int z = 0; z < ksplit; z++) s += Cpart[(long)z * tot + t];
    int a = t / ldC, b = t % ldC;
    C[t] = (a == b) ? 0.f : s;
}

// ---------------- GCN (dense levels): partial-sum pipeline ----------------
__global__ void colsum_part_kernel(const float* __restrict__ A, float* __restrict__ degp, int ld) {
    int i = blockIdx.x * 256 + threadIdx.x;
    int jb = blockIdx.y;
    int j0 = jb * 64;
    float s0 = 0.f, s1 = 0.f, s2 = 0.f, s3 = 0.f, s4 = 0.f, s5 = 0.f, s6 = 0.f, s7 = 0.f;
    const float* p = A + (long)j0 * ld + i;
#pragma unroll
    for (int jq = 0; jq < 64; jq += 8) {
        float v[8];
#pragma unroll
        for (int q = 0; q < 8; q++) v[q] = p[(long)(jq + q) * ld];
        s0 += v[0]; s1 += v[1]; s2 += v[2]; s3 += v[3];
        s4 += v[4]; s5 += v[5]; s6 += v[6]; s7 += v[7];
    }
    float s = ((s0 + s1) + (s2 + s3)) + ((s4 + s5) + (s6 + s7));
    degp[(long)jb * ld + i] = s;
}

__global__ void msgg_kernel(const float* __restrict__ x, const int* __restrict__ perm,
                            const float* __restrict__ vals, const float* __restrict__ Wb,
                            const float* __restrict__ A, int ld, const float* __restrict__ degp,
                            int nparts, float* __restrict__ dis, float* __restrict__ fixb,
                            float* __restrict__ msg, int n) {
    int idx = blockIdx.x * 256 + threadIdx.x;
    if (idx >= n * 32) return;
    int i = idx >> 5, c = idx & 31;
    float dsum = 0.f;
    for (int z = 0; z < nparts; z++) dsum += degp[(long)z * ld + i];
    float diag = A[(long)i * ld + i];
    float fx = diag > 0.f ? 0.f : 2.f;
    float dg = dsum + fx;
    float di = dg > 0.f ? 1.f / sqrtf(dg) : 0.f;
    if (c == 0) { dis[i] = di; fixb[i] = fx; }
    int src = perm ? perm[i] : i;
    float vs = vals ? vals[i] : 1.f;
    float s = 0.f;
#pragma unroll
    for (int q = 0; q < 32; q++) s += x[src * 32 + q] * Wb[q * 32 + c];
    msg[idx] = s * vs * di;
}

__global__ __launch_bounds__(256) void aggT_kernel(const float* __restrict__ A,
                                                   const float* __restrict__ msg,
                                                   float* __restrict__ aggp, int n, int ld, int jchunk) {
    __shared__ float As[64][64];
    __shared__ float Ms[64][32];
    const int tid = threadIdx.x;
    const int i0 = blockIdx.x * 64;
    const int il = tid & 63;
    const int cg = tid >> 6;
    const int i = i0 + il;
    const int mrow = tid >> 2;
    const int mc = (tid & 3) * 8;
    float acc[8];
#pragma unroll
    for (int q = 0; q < 8; q++) acc[q] = 0.f;
    const int j0 = blockIdx.y * jchunk;
    for (int jb = j0; jb < j0 + jchunk; jb += 64) {
        float a16[16], m8[8];
#pragma unroll
        for (int q = 0; q < 16; q++) a16[q] = A[(long)(jb + cg + 4 * q) * ld + i0 + il];
#pragma unroll
        for (int q = 0; q < 8; q++) m8[q] = msg[(long)(jb + mrow) * 32 + mc + q];
        __syncthreads();
#pragma unroll
        for (int q = 0; q < 16; q++) As[cg + 4 * q][il] = a16[q];
#pragma unroll
        for (int q = 0; q < 8; q++) Ms[mrow][mc + q] = m8[q];
        __syncthreads();
#pragma unroll
        for (int jl = 0; jl < 64; jl++) {
            float a = As[jl][il];
#pragma unroll
            for (int q = 0; q < 8; q++) acc[q] += a * Ms[jl][cg * 8 + q];
        }
        __syncthreads();
    }
    if (i < n) {
#pragma unroll
        for (int q = 0; q < 8; q++) aggp[(long)blockIdx.y * APSTR + (long)i * 32 + cg * 8 + q] = acc[q];
    }
}

__global__ void epi_sum_kernel(const float* __restrict__ aggp, int jsplit, const float* __restrict__ msg,
                               const float* __restrict__ dis, const float* __restrict__ fixb,
                               const float* __restrict__ bb, float* __restrict__ out, int n, int relu) {
    int idx = blockIdx.x * 256 + threadIdx.x;
    if (idx >= n * 32) return;
    int i = idx >> 5, c = idx & 31;
    float s = 0.f;
    for (int z = 0; z < jsplit; z++) s += aggp[(long)z * APSTR + idx];
    float v = (s + fixb[i] * msg[idx]) * dis[i] + bb[c];
    if (relu) v = fmaxf(v, 0.f);
    out[idx] = v;
}

// fused epilogue + pooling score/key for next level (down path, relu always on)
__global__ void epi_score_kernel(const float* __restrict__ aggp, int jsplit, const float* __restrict__ msg,
                                 const float* __restrict__ dis, const float* __restrict__ fixb,
                                 const float* __restrict__ bb, const float* __restrict__ p,
                                 float* __restrict__ out, int n, int npow,
                                 unsigned long long* __restrict__ keys) {
    __shared__ float psh[32];
    if (threadIdx.x < 32) psh[threadIdx.x] = p[threadIdx.x];
    __syncthreads();
    int i = blockIdx.x * 256 + threadIdx.x;
    if (i >= npow) return;
    unsigned long long kk = 0ULL;
    if (i < n) {
        float di = dis[i], fx = fixb[i];
        float nrm = 0.f, dot = 0.f;
#pragma unroll 8
        for (int c = 0; c < 32; c++) {
            float s = 0.f;
            for (int z = 0; z < jsplit; z++) s += aggp[(long)z * APSTR + (long)i * 32 + c];
            float v = (s + fx * msg[(long)i * 32 + c]) * di + bb[c];
            v = fmaxf(v, 0.f);
            out[(long)i * 32 + c] = v;
            nrm += psh[c] * psh[c];
            dot += v * psh[c];
        }
        float sc = tanhf(dot / sqrtf(nrm));
        unsigned u = __float_as_uint(sc);
        u = (u & 0x80000000u) ? ~u : (u | 0x80000000u);
        kk = ((unsigned long long)u << 32) | (unsigned)(~i);
    }
    keys[i] = kk;
}

// level-0 msg with inline degree finalize (replaces degfin0 + msg<3,32>)
__global__ void msg0_kernel(const float* __restrict__ x, const float* __restrict__ Wb,
                            const int* __restrict__ rowcntD, const int* __restrict__ diagcnt,
                            float* __restrict__ dis, float* __restrict__ fixb,
                            float* __restrict__ msg, int n) {
    int idx = blockIdx.x * 256 + threadIdx.x;
    if (idx >= n * 32) return;
    int i = idx >> 5, c = idx & 31;
    float fx = diagcnt[i] > 0 ? 0.f : 2.f;
    float dg = (float)rowcntD[i] + fx;
    float di = dg > 0.f ? 1.f / sqrtf(dg) : 0.f;
    if (c == 0) { dis[i] = di; fixb[i] = fx; }
    float s = x[i * 3] * Wb[c] + x[i * 3 + 1] * Wb[32 + c] + x[i * 3 + 2] * Wb[64 + c];
    msg[idx] = s * di;
}

template <int CIN, int COUT>
__global__ void msg_kernel(const float* __restrict__ x, const float* __restrict__ Wb,
                           const float* __restrict__ dis, float* __restrict__ msg, int n) {
    int idx = blockIdx.x * 256 + threadIdx.x;
    if (idx >= n * COUT) return;
    int i = idx / COUT, c = idx % COUT;
    float s = 0.f;
#pragma unroll
    for (int q = 0; q < CIN; q++) s += x[i * CIN + q] * Wb[q * COUT + c];
    msg[idx] = s * dis[i];
}

template <int COUT>
__global__ void cscagg_epi_kernel(const int* __restrict__ rowpD, const int* __restrict__ srcs,
                                  const float* __restrict__ msg, const float* __restrict__ dis,
                                  const float* __restrict__ fixb, const float* __restrict__ bb,
                                  float* __restrict__ out, int n, int relu) {
    int t = blockIdx.x * 256 + threadIdx.x;
    if (t >= n * COUT) return;
    int i = t / COUT, c = t % COUT;
    float acc = 0.f;
    int e0 = rowpD[i], e1 = rowpD[i + 1];
    for (int e = e0; e < e1; e++) acc += msg[(long)srcs[e] * COUT + c];
    float v = (acc + fixb[i] * msg[t]) * dis[i] + bb[c];
    if (relu) v = fmaxf(v, 0.f);
    out[t] = v;
}

// final sparse GCN epilogue + log_softmax fused, writes d_out directly
__global__ void cscagg_lsm_kernel(const int* __restrict__ rowpD, const int* __restrict__ srcs,
                                  const float* __restrict__ msg, const float* __restrict__ dis,
                                  const float* __restrict__ fixb, const float* __restrict__ bb,
                                  float* __restrict__ out, int n) {
    int i = blockIdx.x * 256 + threadIdx.x;
    if (i >= n) return;
    float a0 = 0.f, a1 = 0.f, a2 = 0.f;
    int e0 = rowpD[i], e1 = rowpD[i + 1];
    for (int e = e0; e < e1; e++) {
        const float* m = &msg[(long)srcs[e] * 3];
        a0 += m[0]; a1 += m[1]; a2 += m[2];
    }
    float di = dis[i], fx = fixb[i];
    float v0 = (a0 + fx * msg[i * 3]) * di + bb[0];
    float v1 = (a1 + fx * msg[i * 3 + 1]) * di + bb[1];
    float v2 = (a2 + fx * msg[i * 3 + 2]) * di + bb[2];
    float m = fmaxf(v0, fmaxf(v1, v2));
    float s = expf(v0 - m) + expf(v1 - m) + expf(v2 - m);
    float l = m + logf(s);
    out[i * 3] = v0 - l;
    out[i * 3 + 1] = v1 - l;
    out[i * 3 + 2] = v2 - l;
}

// ---------------- pooling: rank-based exact top-k ----------------
__global__ void score_keys_kernel(const float* __restrict__ x, const float* __restrict__ p,
                                  int n, int npow, unsigned long long* __restrict__ keys) {
    __shared__ float psh[32];
    const int tid = threadIdx.x;
    if (tid < 32) psh[tid] = p[tid];
    __syncthreads();
    int i = blockIdx.x * 256 + tid;
    if (i >= npow) return;
    unsigned long long kk = 0ULL;
    if (i < n) {
        float nrm = 0.f, dot = 0.f;
#pragma unroll
        for (int c = 0; c < 32; c++) {
            nrm += psh[c] * psh[c];
            dot += x[i * 32 + c] * psh[c];
        }
        float sc = tanhf(dot / sqrtf(nrm));
        unsigned u = __float_as_uint(sc);
        u = (u & 0x80000000u) ? ~u : (u | 0x80000000u);
        kk = ((unsigned long long)u << 32) | (unsigned)(~i);
    }
    keys[i] = kk;
}

// rank(i)=#{j: key_j>key_i}. 2-D: block = 16 my-keys x 16 j-chunks; grid = npow/16 blocks.
__global__ __launch_bounds__(256) void topk_rank_kernel(const unsigned long long* __restrict__ keys,
                                                        int npow, int k, int* __restrict__ perm,
                                                        float* __restrict__ vals) {
    __shared__ unsigned long long ks[4096];
    __shared__ int psum[256];
    const int tid = threadIdx.x;
    for (int t = tid; t < npow; t += 256) ks[t] = keys[t];
    __syncthreads();
    const int m = tid & 15;
    const int chunk = tid >> 4;
    const int myi = blockIdx.x * 16 + m;
    unsigned long long my = ks[myi];
    const int cl = npow >> 4;
    const unsigned long long* base = &ks[chunk * cl];
    int r = 0;
#pragma unroll 4
    for (int j = 0; j < cl; j++) r += (base[j] > my) ? 1 : 0;
    psum[chunk * 16 + m] = r;
    __syncthreads();
    if (tid < 16) {
        int mk_i = blockIdx.x * 16 + tid;
        unsigned long long mk = ks[mk_i];
        int rank = 0;
#pragma unroll
        for (int c = 0; c < 16; c++) rank += psum[c * 16 + tid];
        if (rank < k) {
            perm[rank] = (int)(~(unsigned)mk);
            unsigned u = (unsigned)(mk >> 32);
            u = (u & 0x80000000u) ? (u ^ 0x80000000u) : ~u;
            vals[rank] = __uint_as_float(u);
        }
    }
}

__global__ void copy_kernel(float* __restrict__ dst, const float* __restrict__ src, int n) {
    int t = blockIdx.x * 256 + threadIdx.x;
    if (t < n) dst[t] = src[t];
}

__global__ void scatter_add_kernel(float* __restrict__ dst, const float* __restrict__ src,
                                   const int* __restrict__ perm, int k) {
    int t = blockIdx.x * 256 + threadIdx.x;
    if (t >= k * H) return;
    int a = t >> 5, c = t & 31;
    dst[perm[a] * H + c] += src[t];
}

// ---------------- host ----------------
static void run_gcn_dense(hipStream_t st, const float* A, int n, int ld, const float* x,
                          const int* perm, const float* vals, const float* Wt, const float* bt,
                          int relu, float* out, float* degp, float* aggp, float* dis, float* fixb,
                          float* msgb, const float* pnext, int npow_next, unsigned long long* keys) {
    dim3 gcs(ld / 256 > 0 ? ld / 256 : 1, ld / 64);
    colsum_part_kernel<<<gcs, 256, 0, st>>>(A, degp, ld);
    int gm = (n * H + 255) / 256;
    msgg_kernel<<<gm, 256, 0, st>>>(x, perm, vals, Wt, A, ld, degp, ld / 64, dis, fixb, msgb, n);
    int jsplit = ld / 256 > 0 ? ld / 256 : 1;
    int ajc = ld / jsplit;
    dim3 ga(ld / 64, jsplit);
    aggT_kernel<<<ga, 256, 0, st>>>(A, msgb, aggp, n, ld, ajc);
    if (pnext) {
        epi_score_kernel<<<(npow_next + 255) / 256, 256, 0, st>>>(aggp, jsplit, msgb, dis, fixb, bt,
                                                                  pnext, out, n, npow_next, keys);
    } else {
        epi_sum_kernel<<<gm, 256, 0, st>>>(aggp, jsplit, msgb, dis, fixb, bt, out, n, relu);
    }
}

extern "C" void kernel_launch(void* const* d_in, const int* in_sizes, int n_in,
                              void* d_out, int out_size, void* d_ws, size_t ws_size,
                              hipStream_t stream) {
    const float* x0f = (const float*)d_in[0];
    const int* eidx = (const int*)d_in[1];
    const float* W0f = (const float*)d_in[2];
    const float* b0f = (const float*)d_in[3];
    const float* Wdf = (const float*)d_in[4];
    const float* bdf = (const float*)d_in[5];
    const float* Pf = (const float*)d_in[6];
    const float* Wuf = (const float*)d_in[7];
    const float* buf2 = (const float*)d_in[8];
    const float* Wlf = (const float*)d_in[9];
    const float* blf = (const float*)d_in[10];
    const int E = in_sizes[1] / 2;

    unsigned char* w = (unsigned char*)d_ws;
    size_t off = 0;
    auto alloc = [&](size_t bytes) -> void* {
        void* p = w + off;
        off += (bytes + 255) & ~(size_t)255;
        return p;
    };
    int* rowcnt = (int*)alloc(N0 * 4);
    int* rowcntD = (int*)alloc(N0 * 4);
    int* diagcnt = (int*)alloc(N0 * 4);
    int* rowp = (int*)alloc((N0 + 1) * 4);
    int* rowpD = (int*)alloc((N0 + 1) * 4);
    int* cursor = (int*)alloc(N0 * 4);
    int* cursorD = (int*)alloc(N0 * 4);
    int* cols = (int*)alloc((size_t)EMAX * 4);
    int* srcs = (int*)alloc((size_t)EMAX * 4);
    int* invperm = (int*)alloc(N0 * 4);
    float* dis0 = (float*)alloc(N0 * 4);
    float* fixb0 = (float*)alloc(N0 * 4);
    unsigned long long* keys = (unsigned long long*)alloc((size_t)N0 * 8);
    float* A1 = (float*)alloc((size_t)2048 * 2048 * 4);
    float* A2 = (float*)alloc((size_t)1024 * 1024 * 4);
    float* A3 = (float*)alloc((size_t)512 * 512 * 4);
    float* A4 = (float*)alloc((size_t)256 * 256 * 4);
    float* Gr = (float*)alloc((size_t)1024 * 2048 * 4);
    float* Gc = (float*)alloc((size_t)2048 * 1024 * 4);
    unsigned short* Grb = (unsigned short*)alloc((size_t)1024 * 2048 * 2);
    unsigned short* GcTb = (unsigned short*)alloc((size_t)1024 * 2048 * 2);
    float* Cpart = (float*)alloc((size_t)8 * 512 * 512 * 4);
    float* degp = (float*)alloc((size_t)32 * 2048 * 4);
    float* aggp = (float*)alloc((size_t)8 * APSTR * 4);
    float* xs0 = (float*)alloc((size_t)N0 * H * 4);
    float* xs1 = (float*)alloc((size_t)2000 * H * 4);
    float* xs2 = (float*)alloc((size_t)1000 * H * 4);
    float* xs3 = (float*)alloc((size_t)500 * H * 4);
    float* xtA = (float*)alloc((size_t)N0 * H * 4);
    float* xtB = (float*)alloc((size_t)N0 * H * 4);
    float* msgb = (float*)alloc((size_t)N0 * H * 4);
    float* dis = (float*)alloc(N0 * 4);
    float* fixb = (float*)alloc(N0 * 4);
    const int ksz[4] = {2000, 1000, 500, 250};
    int* perm[4];
    float* vals[4];
    for (int i = 0; i < 4; i++) perm[i] = (int*)alloc((size_t)ksz[i] * 4);
    for (int i = 0; i < 4; i++) vals[i] = (float*)alloc((size_t)ksz[i] * 4);

    if (off > ws_size) {
        fill_sentinel_kernel<<<(out_size + 255) / 256, 256, 0, stream>>>((float*)d_out, out_size);
        return;
    }

    const int nlvl[5] = {N0, 2000, 1000, 500, 250};
    const int ldl[5] = {N0, 2048, 1024, 512, 256};
    const int npw[4] = {4096, 2048, 1024, 512};
    float* Afp[5] = {nullptr, A1, A2, A3, A4};
    float* xsb[4] = {xs0, xs1, xs2, xs3};

    // ---- CSR build + level-0 stats ----
    hipMemsetAsync(rowcnt, 0, (size_t)N0 * 3 * 4, stream);
    build_stats_kernel<<<(E + 255) / 256, 256, 0, stream>>>(eidx, E, rowcnt, rowcntD, diagcnt);
    scan2_kernel<<<1, 1024, 0, stream>>>(rowcnt, rowp, cursor, rowcntD, rowpD, cursorD);
    fill_csr_kernel<<<(E + 255) / 256, 256, 0, stream>>>(eidx, E, cursor, cols, cursorD, srcs);

    // ---- GCN level 0 (sparse, 3->32, relu); degfin fused into msg0 ----
    msg0_kernel<<<(N0 * H + 255) / 256, 256, 0, stream>>>(x0f, W0f, rowcntD, diagcnt, dis0, fixb0,
                                                          msgb, N0);
    cscagg_epi_kernel<H><<<(N0 * H + 255) / 256, 256, 0, stream>>>(rowpD, srcs, msgb, dis0, fixb0,
                                                                   b0f, xs0, N0, 1);
    float* xcur = xs0;

    // ---- down path ----
    for (int i = 0; i < 4; ++i) {
        int nd = nlvl[i], kk = ksz[i], ldn = ldl[i + 1];
        if (i == 0)
            score_keys_kernel<<<(npw[0] + 255) / 256, 256, 0, stream>>>(xcur, Pf, nd, npw[0], keys);
        // (for i>0, keys were produced by epi_score of the previous GCN)
        topk_rank_kernel<<<npw[i] / 16, 256, 0, stream>>>(keys, npw[i], kk, perm[i], vals[i]);
        if (i == 0) {
            hipMemsetAsync(invperm, 0xFF, (size_t)N0 * 4, stream);
            invperm_set_kernel<<<(kk + 255) / 256, 256, 0, stream>>>(perm[0], invperm, kk);
            aug0_kernel<<<ldn, 256, 0, stream>>>(rowp, cols, perm[0], invperm, kk, ldn, A1);
        } else if (i == 1) {
            int ldM = ldl[i];
            dim3 gr((ldM + 255) / 256, ldn);
            gather_rows_bf16_kernel<<<gr, 256, 0, stream>>>(Afp[i], ldM, perm[i], kk, Grb);
            dim3 gt(ldn / 32, ldM / 32);
            gather_colsT_bf16_kernel<<<gt, dim3(32, 8), 0, stream>>>(Afp[i], ldM, perm[i], kk, GcTb);
            hipMemsetAsync(Afp[i + 1], 0, (size_t)ldn * ldn * 4, stream);
            int ksplit = 4;
            int kchunk = ldM / ksplit;
            dim3 gg(ldn / 64, ldn / 64, ksplit);
            mfma_aug_kernel<<<gg, 256, 0, stream>>>(Grb, GcTb, Afp[i + 1], ldM, ldn, kchunk);
        } else {
            int ldM = ldl[i];
            dim3 gr((ldM + 255) / 256, ldn);
            gather_rows_kernel<<<gr, 256, 0, stream>>>(Afp[i], ldM, perm[i], kk, Gr);
            dim3 gc((ldn + 255) / 256, ldM);
            gather_cols_kernel<<<gc, 256, 0, stream>>>(Afp[i], ldM, perm[i], kk, Gc, ldn);
            int ksplit = 8;
            int kchunk = ldM / ksplit;
            dim3 gg(ldn / 64, ldn / 64, ksplit);
            gemm64_kernel<<<gg, 256, 0, stream>>>(Gr, Gc, Cpart, ldM, ldn, kchunk);
            long tot = (long)ldn * ldn;
            reduce_part_kernel<<<(tot + 255) / 256, 256, 0, stream>>>(Cpart, Afp[i + 1], ldn, ksplit);
        }
        float* outx = (i < 3) ? xsb[i + 1] : xtB;
        const float* pnext = (i < 3) ? (Pf + (i + 1) * H) : nullptr;
        int npow_next = (i < 3) ? npw[i + 1] : 0;
        run_gcn_dense(stream, Afp[i + 1], kk, ldn, xcur, perm[i], vals[i], Wdf + i * (H * H),
                      bdf + i * H, 1, outx, degp, aggp, dis, fixb, msgb, pnext, npow_next, keys);
        xcur = outx;
    }

    // ---- up path ----
    for (int i = 0; i < 4; ++i) {
        int j = 3 - i;
        int nj = nlvl[j], kj = ksz[j];
        copy_kernel<<<(nj * H + 255) / 256, 256, 0, stream>>>(xtA, xsb[j], nj * H);
        scatter_add_kernel<<<(kj * H + 255) / 256, 256, 0, stream>>>(xtA, xcur, perm[j], kj);
        if (i < 3) {
            run_gcn_dense(stream, Afp[j], nj, ldl[j], xtA, nullptr, nullptr, Wuf + i * (H * H),
                          buf2 + i * H, 1, xtB, degp, aggp, dis, fixb, msgb, nullptr, 0, nullptr);
        } else {
            msg_kernel<H, 3><<<(N0 * 3 + 255) / 256, 256, 0, stream>>>(xtA, Wlf, dis0, msgb, N0);
            cscagg_lsm_kernel<<<(N0 + 255) / 256, 256, 0, stream>>>(rowpD, srcs, msgb, dis0, fixb0,
                                                                    blf, (float*)d_out, N0);
        }
        xcur = xtB;
    }
}

// Round 19
// 477.475 us; speedup vs baseline: 1.1703x; 1.1703x over previous
//
#include <hip/hip_runtime.h>
#include <math.h>

#define H 32
#define N0 4096
#define EMAX 131072
#define APSTR (4096 * 32)

typedef __attribute__((ext_vector_type(4))) float floatx4;
typedef __attribute__((ext_vector_type(8))) short short8;

__device__ __forceinline__ unsigned short f2bf_bits(float v) {
    union { float f; unsigned u; } c;
    c.f = v;
    unsigned lsb = (c.u >> 16) & 1u;
    c.u += 0x7fffu + lsb;   // RNE; inputs here are small exact integers
    return (unsigned short)(c.u >> 16);
}

// ---------------- sentinel ----------------
__global__ void fill_sentinel_kernel(float* out, int n) {
    int t = blockIdx.x * 256 + threadIdx.x;
    if (t < n) out[t] = 9.0f;
}

// ---------------- CSR build ----------------
__global__ void build_stats_kernel(const int* __restrict__ ei, int E, int* __restrict__ rowcnt,
                                   int* __restrict__ rowcntD, int* __restrict__ diagcnt) {
    int t = blockIdx.x * 256 + threadIdx.x;
    if (t >= E) return;
    int s = ei[t], d = ei[E + t];
    if ((unsigned)s >= N0 || (unsigned)d >= N0) return;
    atomicAdd(&rowcnt[s], 1);
    atomicAdd(&rowcntD[d], 1);
    if (s == d) atomicAdd(&diagcnt[s], 1);
}

// both scans + cursor copies in one launch
__global__ __launch_bounds__(1024) void scan2_kernel(const int* __restrict__ cntA, int* __restrict__ rowpA,
                                                     int* __restrict__ curA, const int* __restrict__ cntB,
                                                     int* __restrict__ rowpB, int* __restrict__ curB) {
    __shared__ int part[1024];
    int tid = threadIdx.x;
    for (int pass = 0; pass < 2; pass++) {
        const int* cnt = pass ? cntB : cntA;
        int* rowp = pass ? rowpB : rowpA;
        int* cur = pass ? curB : curA;
        int base = tid * 4;
        int local[4];
        int s = 0;
#pragma unroll
        for (int i = 0; i < 4; i++) { local[i] = s; s += cnt[base + i]; }
        part[tid] = s;
        __syncthreads();
        for (int off = 1; off < 1024; off <<= 1) {
            int v = (tid >= off) ? part[tid - off] : 0;
            __syncthreads();
            part[tid] += v;
            __syncthreads();
        }
        int pre = (tid == 0) ? 0 : part[tid - 1];
#pragma unroll
        for (int i = 0; i < 4; i++) { rowp[base + i] = pre + local[i]; cur[base + i] = pre + local[i]; }
        if (tid == 1023) rowp[N0] = pre + s;
        __syncthreads();
    }
}

__global__ void fill_csr_kernel(const int* __restrict__ ei, int E, int* __restrict__ cursor,
                                int* __restrict__ cols, int* __restrict__ cursorD,
                                int* __restrict__ srcs) {
    int t = blockIdx.x * 256 + threadIdx.x;
    if (t >= E) return;
    int s = ei[t], d = ei[E + t];
    if ((unsigned)s >= N0 || (unsigned)d >= N0) return;
    int pos = atomicAdd(&cursor[s], 1);
    cols[pos] = d;
    int posD = atomicAdd(&cursorD[d], 1);
    srcs[posD] = s;
}

__global__ void invperm_set_kernel(const int* __restrict__ perm, int* __restrict__ invperm, int k) {
    int t = blockIdx.x * 256 + threadIdx.x;
    if (t < k) invperm[perm[t]] = t;
}

// ---------------- level-0 fused augment+pool ----------------
__global__ __launch_bounds__(256) void aug0_kernel(const int* __restrict__ rowp, const int* __restrict__ cols,
                                                   const int* __restrict__ perm, const int* __restrict__ invperm,
                                                   int kOut, int ldC, float* __restrict__ C) {
    __shared__ float row[2048];
    int a = blockIdx.x;
    int tid = threadIdx.x;
    for (int j = tid; j < ldC; j += 256) row[j] = 0.f;
    __syncthreads();
    if (a < kOut) {
        int pa = perm[a];
        int s0 = rowp[pa], s1 = rowp[pa + 1];
        for (int e = s0 + tid; e < s1; e += 256) {
            int k = cols[e];
            int ip = invperm[k];
            if (ip >= 0) atomicAdd(&row[ip], 2.0f);
            int t1 = rowp[k + 1];
            for (int e2 = rowp[k]; e2 < t1; ++e2) {
                int ip2 = invperm[cols[e2]];
                if (ip2 >= 0) atomicAdd(&row[ip2], 1.0f);
            }
        }
    }
    __syncthreads();
    for (int j = tid; j < ldC; j += 256) C[(long)a * ldC + j] = (j == a) ? 0.f : row[j];
}

// ---------------- deeper levels: pre-gathered operands + GEMM ----------------
__global__ void gather_rows_kernel(const float* __restrict__ M, int ldM, const int* __restrict__ perm,
                                   int kOut, float* __restrict__ Gr) {
    int k = blockIdx.x * 256 + threadIdx.x;
    int a = blockIdx.y;
    if (k >= ldM) return;
    float v = 0.f;
    if (a < kOut) {
        int pa = perm[a];
        v = M[(long)pa * ldM + k] + (k == pa ? 1.f : 0.f);
    }
    Gr[(long)a * ldM + k] = v;
}

__global__ void gather_rows_bf16_kernel(const float* __restrict__ M, int ldM, const int* __restrict__ perm,
                                        int kOut, unsigned short* __restrict__ Gr) {
    int k = blockIdx.x * 256 + threadIdx.x;
    int a = blockIdx.y;
    if (k >= ldM) return;
    float v = 0.f;
    if (a < kOut) {
        int pa = perm[a];
        v = M[(long)pa * ldM + k] + (k == pa ? 1.f : 0.f);
    }
    Gr[(long)a * ldM + k] = f2bf_bits(v);
}

__global__ void gather_cols_kernel(const float* __restrict__ M, int ldM, const int* __restrict__ perm,
                                   int kOut, float* __restrict__ Gc, int ldC) {
    int b = blockIdx.x * 256 + threadIdx.x;
    int k = blockIdx.y;
    if (b >= ldC) return;
    float v = 0.f;
    if (b < kOut) {
        int pb = perm[b];
        v = M[(long)k * ldM + pb] + (k == pb ? 1.f : 0.f);
    }
    Gc[(long)k * ldC + b] = v;
}

// fused gather+transpose+cvt: GcT[b][k] = bf16((M+I)[k, perm[b]]). Grid (ldn/32, ldM/32), block (32,8)
__global__ void gather_colsT_bf16_kernel(const float* __restrict__ M, int ldM,
                                         const int* __restrict__ perm, int kOut,
                                         unsigned short* __restrict__ GcT) {
    __shared__ float t[32][33];
    __shared__ int pb[32];
    int b0 = blockIdx.x * 32, k0 = blockIdx.y * 32;
    int tx = threadIdx.x, ty = threadIdx.y;
    if (ty == 0) pb[tx] = (b0 + tx < kOut) ? perm[b0 + tx] : -1;
    __syncthreads();
    for (int y = ty; y < 32; y += 8) {
        int k = k0 + y;
        int pbx = pb[tx];
        float v = 0.f;
        if (pbx >= 0) v = M[(long)k * ldM + pbx] + (k == pbx ? 1.f : 0.f);
        t[y][tx] = v;
    }
    __syncthreads();
    for (int y = ty; y < 32; y += 8)
        GcT[(long)(b0 + y) * ldM + k0 + tx] = f2bf_bits(t[tx][y]);
}

__global__ __launch_bounds__(256) void mfma_aug_kernel(const unsigned short* __restrict__ Aop,
                                                       const unsigned short* __restrict__ Bop,
                                                       float* __restrict__ C, int K, int ldC, int kchunk) {
    __shared__ __align__(16) unsigned short lA[64 * 32];
    __shared__ __align__(16) unsigned short lB[64 * 32];
    const int tid = threadIdx.x;
    const int lane = tid & 63;
    const int w = tid >> 6;
    const int a0 = blockIdx.y * 64, b0 = blockIdx.x * 64;
    const int kbase = blockIdx.z * kchunk;
    const int r0 = tid >> 2;
    const int c8 = (tid & 3) * 8;
    const unsigned short* gA = Aop + (long)(a0 + r0) * K + kbase + c8;
    const unsigned short* gB = Bop + (long)(b0 + r0) * K + kbase + c8;
    const int wm = (w & 1) * 32;
    const int wn = (w >> 1) * 32;
    const int lm = lane & 15;
    const int quad = lane >> 4;
    floatx4 acc[2][2];
#pragma unroll
    for (int i = 0; i < 2; i++)
#pragma unroll
        for (int j = 0; j < 2; j++) {
            floatx4 z = {0.f, 0.f, 0.f, 0.f};
            acc[i][j] = z;
        }
    for (int k0 = 0; k0 < kchunk; k0 += 32) {
        short8 va = *(const short8*)(gA + k0);
        short8 vb = *(const short8*)(gB + k0);
        __syncthreads();
        *(short8*)&lA[r0 * 32 + c8] = va;
        *(short8*)&lB[r0 * 32 + c8] = vb;
        __syncthreads();
        short8 af[2], bf[2];
#pragma unroll
        for (int mi = 0; mi < 2; mi++) af[mi] = *(const short8*)&lA[(wm + mi * 16 + lm) * 32 + quad * 8];
#pragma unroll
        for (int ni = 0; ni < 2; ni++) bf[ni] = *(const short8*)&lB[(wn + ni * 16 + lm) * 32 + quad * 8];
#pragma unroll
        for (int mi = 0; mi < 2; mi++)
#pragma unroll
            for (int ni = 0; ni < 2; ni++)
                acc[mi][ni] = __builtin_amdgcn_mfma_f32_16x16x32_bf16(af[mi], bf[ni], acc[mi][ni], 0, 0, 0);
    }
#pragma unroll
    for (int mi = 0; mi < 2; mi++)
#pragma unroll
        for (int ni = 0; ni < 2; ni++) {
            int col = b0 + wn + ni * 16 + lm;
#pragma unroll
            for (int r = 0; r < 4; r++) {
                int row = a0 + wm + mi * 16 + quad * 4 + r;
                if (row != col) atomicAdd(&C[(long)row * ldC + col], acc[mi][ni][r]);
            }
        }
}

__global__ __launch_bounds__(256) void gemm64_kernel(const float* __restrict__ Gr,
                                                     const float* __restrict__ Gc,
                                                     float* __restrict__ Cpart, int K, int ldC, int kchunk) {
    __shared__ float As[32][68];
    __shared__ float Bs[32][68];
    const int tid = threadIdx.x;
    const int a0 = blockIdx.y * 64, b0 = blockIdx.x * 64;
    const int kbase = blockIdx.z * kchunk;
    float* Cz = Cpart + (long)blockIdx.z * ldC * ldC;
    const int tx = tid & 15, ty = tid >> 4;
    const int lr = tid >> 2;
    const int lk = (tid & 3) * 8;
    const int bb = tid & 63;
    const int kr = (tid >> 6) * 8;
    const float* gA = Gr + (long)(a0 + lr) * K + lk + kbase;
    const float* gB = Gc + (long)(kr + kbase) * ldC + b0 + bb;
    float acc[4][4];
#pragma unroll
    for (int i = 0; i < 4; i++)
#pragma unroll
        for (int j = 0; j < 4; j++) acc[i][j] = 0.f;
    for (int k0 = 0; k0 < kchunk; k0 += 32) {
        float a8[8], b8[8];
#pragma unroll
        for (int i = 0; i < 8; i++) a8[i] = gA[k0 + i];
#pragma unroll
        for (int i = 0; i < 8; i++) b8[i] = gB[(long)(k0 + i) * ldC];
        __syncthreads();
#pragma unroll
        for (int i = 0; i < 8; i++) As[lk + i][lr] = a8[i];
#pragma unroll
        for (int i = 0; i < 8; i++) Bs[kr + i][bb] = b8[i];
        __syncthreads();
#pragma unroll
        for (int k = 0; k < 32; k++) {
            floatx4 av = *(const floatx4*)&As[k][ty * 4];
            floatx4 bv = *(const floatx4*)&Bs[k][tx * 4];
#pragma unroll
            for (int i = 0; i < 4; i++)
#pragma unroll
                for (int j = 0; j < 4; j++) acc[i][j] += av[i] * bv[j];
        }
    }
#pragma unroll
    for (int i = 0; i < 4; i++)
#pragma unroll
        for (int j = 0; j < 4; j++) {
            int a = a0 + ty * 4 + i, b = b0 + tx * 4 + j;
            Cz[(long)a * ldC + b] = acc[i][j];
        }
}

__global__ void reduce_part_kernel(const float* __restrict__ Cpart, float* __restrict__ C,
                                   int ldC, int ksplit) {
    int t = blockIdx.x * 256 + threadIdx.x;
    long tot = (long)ldC * ldC;
    if (t >= tot) return;
    float s = 0.f;
    for (int z = 0; z < ksplit; z++) s += Cpart[(long)z * tot + t];
    int a = t / ldC, b = t % ldC;
    C[t] = (a == b) ? 0.f : s;
}

// ---------------- GCN (dense levels): partial-sum pipeline ----------------
__global__ void colsum_part_kernel(const float* __restrict__ A, float* __restrict__ degp, int ld) {
    int i = blockIdx.x * 256 + threadIdx.x;
    int jb = blockIdx.y;
    int j0 = jb * 64;
    float s0 = 0.f, s1 = 0.f, s2 = 0.f, s3 = 0.f, s4 = 0.f, s5 = 0.f, s6 = 0.f, s7 = 0.f;
    const float* p = A + (long)j0 * ld + i;
#pragma unroll
    for (int jq = 0; jq < 64; jq += 8) {
        float v[8];
#pragma unroll
        for (int q = 0; q < 8; q++) v[q] = p[(long)(jq + q) * ld];
        s0 += v[0]; s1 += v[1]; s2 += v[2]; s3 += v[3];
        s4 += v[4]; s5 += v[5]; s6 += v[6]; s7 += v[7];
    }
    float s = ((s0 + s1) + (s2 + s3)) + ((s4 + s5) + (s6 + s7));
    degp[(long)jb * ld + i] = s;
}

__global__ void msgg_kernel(const float* __restrict__ x, const int* __restrict__ perm,
                            const float* __restrict__ vals, const float* __restrict__ Wb,
                            const float* __restrict__ A, int ld, const float* __restrict__ degp,
                            int nparts, float* __restrict__ dis, float* __restrict__ fixb,
                            float* __restrict__ msg, int n) {
    int idx = blockIdx.x * 256 + threadIdx.x;
    if (idx >= n * 32) return;
    int i = idx >> 5, c = idx & 31;
    float dsum = 0.f;
    for (int z = 0; z < nparts; z++) dsum += degp[(long)z * ld + i];
    float diag = A[(long)i * ld + i];
    float fx = diag > 0.f ? 0.f : 2.f;
    float dg = dsum + fx;
    float di = dg > 0.f ? 1.f / sqrtf(dg) : 0.f;
    if (c == 0) { dis[i] = di; fixb[i] = fx; }
    int src = perm ? perm[i] : i;
    float vs = vals ? vals[i] : 1.f;
    float s = 0.f;
#pragma unroll
    for (int q = 0; q < 32; q++) s += x[src * 32 + q] * Wb[q * 32 + c];
    msg[idx] = s * vs * di;
}

__global__ __launch_bounds__(256) void aggT_kernel(const float* __restrict__ A,
                                                   const float* __restrict__ msg,
                                                   float* __restrict__ aggp, int n, int ld, int jchunk) {
    __shared__ float As[64][64];
    __shared__ float Ms[64][32];
    const int tid = threadIdx.x;
    const int i0 = blockIdx.x * 64;
    const int il = tid & 63;
    const int cg = tid >> 6;
    const int i = i0 + il;
    const int mrow = tid >> 2;
    const int mc = (tid & 3) * 8;
    float acc[8];
#pragma unroll
    for (int q = 0; q < 8; q++) acc[q] = 0.f;
    const int j0 = blockIdx.y * jchunk;
    for (int jb = j0; jb < j0 + jchunk; jb += 64) {
        float a16[16], m8[8];
#pragma unroll
        for (int q = 0; q < 16; q++) a16[q] = A[(long)(jb + cg + 4 * q) * ld + i0 + il];
#pragma unroll
        for (int q = 0; q < 8; q++) m8[q] = msg[(long)(jb + mrow) * 32 + mc + q];
        __syncthreads();
#pragma unroll
        for (int q = 0; q < 16; q++) As[cg + 4 * q][il] = a16[q];
#pragma unroll
        for (int q = 0; q < 8; q++) Ms[mrow][mc + q] = m8[q];
        __syncthreads();
#pragma unroll
        for (int jl = 0; jl < 64; jl++) {
            float a = As[jl][il];
#pragma unroll
            for (int q = 0; q < 8; q++) acc[q] += a * Ms[jl][cg * 8 + q];
        }
        __syncthreads();
    }
    if (i < n) {
#pragma unroll
        for (int q = 0; q < 8; q++) aggp[(long)blockIdx.y * APSTR + (long)i * 32 + cg * 8 + q] = acc[q];
    }
}

__global__ void epi_sum_kernel(const float* __restrict__ aggp, int jsplit, const float* __restrict__ msg,
                               const float* __restrict__ dis, const float* __restrict__ fixb,
                               const float* __restrict__ bb, float* __restrict__ out, int n, int relu) {
    int idx = blockIdx.x * 256 + threadIdx.x;
    if (idx >= n * 32) return;
    int i = idx >> 5, c = idx & 31;
    float s = 0.f;
    for (int z = 0; z < jsplit; z++) s += aggp[(long)z * APSTR + idx];
    float v = (s + fixb[i] * msg[idx]) * dis[i] + bb[c];
    if (relu) v = fmaxf(v, 0.f);
    out[idx] = v;
}

// level-0 msg with inline degree finalize (replaces degfin0 + msg<3,32>)
__global__ void msg0_kernel(const float* __restrict__ x, const float* __restrict__ Wb,
                            const int* __restrict__ rowcntD, const int* __restrict__ diagcnt,
                            float* __restrict__ dis, float* __restrict__ fixb,
                            float* __restrict__ msg, int n) {
    int idx = blockIdx.x * 256 + threadIdx.x;
    if (idx >= n * 32) return;
    int i = idx >> 5, c = idx & 31;
    float fx = diagcnt[i] > 0 ? 0.f : 2.f;
    float dg = (float)rowcntD[i] + fx;
    float di = dg > 0.f ? 1.f / sqrtf(dg) : 0.f;
    if (c == 0) { dis[i] = di; fixb[i] = fx; }
    float s = x[i * 3] * Wb[c] + x[i * 3 + 1] * Wb[32 + c] + x[i * 3 + 2] * Wb[64 + c];
    msg[idx] = s * di;
}

template <int CIN, int COUT>
__global__ void msg_kernel(const float* __restrict__ x, const float* __restrict__ Wb,
                           const float* __restrict__ dis, float* __restrict__ msg, int n) {
    int idx = blockIdx.x * 256 + threadIdx.x;
    if (idx >= n * COUT) return;
    int i = idx / COUT, c = idx % COUT;
    float s = 0.f;
#pragma unroll
    for (int q = 0; q < CIN; q++) s += x[i * CIN + q] * Wb[q * COUT + c];
    msg[idx] = s * dis[i];
}

template <int COUT>
__global__ void cscagg_epi_kernel(const int* __restrict__ rowpD, const int* __restrict__ srcs,
                                  const float* __restrict__ msg, const float* __restrict__ dis,
                                  const float* __restrict__ fixb, const float* __restrict__ bb,
                                  float* __restrict__ out, int n, int relu) {
    int t = blockIdx.x * 256 + threadIdx.x;
    if (t >= n * COUT) return;
    int i = t / COUT, c = t % COUT;
    float acc = 0.f;
    int e0 = rowpD[i], e1 = rowpD[i + 1];
    for (int e = e0; e < e1; e++) acc += msg[(long)srcs[e] * COUT + c];
    float v = (acc + fixb[i] * msg[t]) * dis[i] + bb[c];
    if (relu) v = fmaxf(v, 0.f);
    out[t] = v;
}

// final sparse GCN epilogue + log_softmax fused, writes d_out directly
__global__ void cscagg_lsm_kernel(const int* __restrict__ rowpD, const int* __restrict__ srcs,
                                  const float* __restrict__ msg, const float* __restrict__ dis,
                                  const float* __restrict__ fixb, const float* __restrict__ bb,
                                  float* __restrict__ out, int n) {
    int i = blockIdx.x * 256 + threadIdx.x;
    if (i >= n) return;
    float a0 = 0.f, a1 = 0.f, a2 = 0.f;
    int e0 = rowpD[i], e1 = rowpD[i + 1];
    for (int e = e0; e < e1; e++) {
        const float* m = &msg[(long)srcs[e] * 3];
        a0 += m[0]; a1 += m[1]; a2 += m[2];
    }
    float di = dis[i], fx = fixb[i];
    float v0 = (a0 + fx * msg[i * 3]) * di + bb[0];
    float v1 = (a1 + fx * msg[i * 3 + 1]) * di + bb[1];
    float v2 = (a2 + fx * msg[i * 3 + 2]) * di + bb[2];
    float m = fmaxf(v0, fmaxf(v1, v2));
    float s = expf(v0 - m) + expf(v1 - m) + expf(v2 - m);
    float l = m + logf(s);
    out[i * 3] = v0 - l;
    out[i * 3 + 1] = v1 - l;
    out[i * 3 + 2] = v2 - l;
}

// ---------------- pooling: rank-based exact top-k ----------------
__global__ void score_keys_kernel(const float* __restrict__ x, const float* __restrict__ p,
                                  int n, int npow, unsigned long long* __restrict__ keys) {
    __shared__ float psh[32];
    const int tid = threadIdx.x;
    if (tid < 32) psh[tid] = p[tid];
    __syncthreads();
    int i = blockIdx.x * 256 + tid;
    if (i >= npow) return;
    unsigned long long kk = 0ULL;
    if (i < n) {
        float nrm = 0.f, dot = 0.f;
#pragma unroll
        for (int c = 0; c < 32; c++) {
            nrm += psh[c] * psh[c];
            dot += x[i * 32 + c] * psh[c];
        }
        float sc = tanhf(dot / sqrtf(nrm));
        unsigned u = __float_as_uint(sc);
        u = (u & 0x80000000u) ? ~u : (u | 0x80000000u);
        kk = ((unsigned long long)u << 32) | (unsigned)(~i);
    }
    keys[i] = kk;
}

// rank(i)=#{j: key_j>key_i}. 2-D: block = 16 my-keys x 16 j-chunks; grid = npow/16 blocks.
__global__ __launch_bounds__(256) void topk_rank_kernel(const unsigned long long* __restrict__ keys,
                                                        int npow, int k, int* __restrict__ perm,
                                                        float* __restrict__ vals) {
    __shared__ unsigned long long ks[4096];
    __shared__ int psum[256];
    const int tid = threadIdx.x;
    for (int t = tid; t < npow; t += 256) ks[t] = keys[t];
    __syncthreads();
    const int m = tid & 15;
    const int chunk = tid >> 4;
    const int myi = blockIdx.x * 16 + m;
    unsigned long long my = ks[myi];
    const int cl = npow >> 4;
    const unsigned long long* base = &ks[chunk * cl];
    int r = 0;
#pragma unroll 4
    for (int j = 0; j < cl; j++) r += (base[j] > my) ? 1 : 0;
    psum[chunk * 16 + m] = r;
    __syncthreads();
    if (tid < 16) {
        int mk_i = blockIdx.x * 16 + tid;
        unsigned long long mk = ks[mk_i];
        int rank = 0;
#pragma unroll
        for (int c = 0; c < 16; c++) rank += psum[c * 16 + tid];
        if (rank < k) {
            perm[rank] = (int)(~(unsigned)mk);
            unsigned u = (unsigned)(mk >> 32);
            u = (u & 0x80000000u) ? (u ^ 0x80000000u) : ~u;
            vals[rank] = __uint_as_float(u);
        }
    }
}

__global__ void copy_kernel(float* __restrict__ dst, const float* __restrict__ src, int n) {
    int t = blockIdx.x * 256 + threadIdx.x;
    if (t < n) dst[t] = src[t];
}

__global__ void scatter_add_kernel(float* __restrict__ dst, const float* __restrict__ src,
                                   const int* __restrict__ perm, int k) {
    int t = blockIdx.x * 256 + threadIdx.x;
    if (t >= k * H) return;
    int a = t >> 5, c = t & 31;
    dst[perm[a] * H + c] += src[t];
}

// ---------------- host ----------------
static void run_gcn_dense(hipStream_t st, const float* A, int n, int ld, const float* x,
                          const int* perm, const float* vals, const float* Wt, const float* bt,
                          int relu, float* out, float* degp, float* aggp, float* dis, float* fixb,
                          float* msgb) {
    dim3 gcs(ld / 256 > 0 ? ld / 256 : 1, ld / 64);
    colsum_part_kernel<<<gcs, 256, 0, st>>>(A, degp, ld);
    int gm = (n * H + 255) / 256;
    msgg_kernel<<<gm, 256, 0, st>>>(x, perm, vals, Wt, A, ld, degp, ld / 64, dis, fixb, msgb, n);
    int jsplit = ld / 256 > 0 ? ld / 256 : 1;
    int ajc = ld / jsplit;
    dim3 ga(ld / 64, jsplit);
    aggT_kernel<<<ga, 256, 0, st>>>(A, msgb, aggp, n, ld, ajc);
    epi_sum_kernel<<<gm, 256, 0, st>>>(aggp, jsplit, msgb, dis, fixb, bt, out, n, relu);
}

extern "C" void kernel_launch(void* const* d_in, const int* in_sizes, int n_in,
                              void* d_out, int out_size, void* d_ws, size_t ws_size,
                              hipStream_t stream) {
    const float* x0f = (const float*)d_in[0];
    const int* eidx = (const int*)d_in[1];
    const float* W0f = (const float*)d_in[2];
    const float* b0f = (const float*)d_in[3];
    const float* Wdf = (const float*)d_in[4];
    const float* bdf = (const float*)d_in[5];
    const float* Pf = (const float*)d_in[6];
    const float* Wuf = (const float*)d_in[7];
    const float* buf2 = (const float*)d_in[8];
    const float* Wlf = (const float*)d_in[9];
    const float* blf = (const float*)d_in[10];
    const int E = in_sizes[1] / 2;

    unsigned char* w = (unsigned char*)d_ws;
    size_t off = 0;
    auto alloc = [&](size_t bytes) -> void* {
        void* p = w + off;
        off += (bytes + 255) & ~(size_t)255;
        return p;
    };
    int* rowcnt = (int*)alloc(N0 * 4);
    int* rowcntD = (int*)alloc(N0 * 4);
    int* diagcnt = (int*)alloc(N0 * 4);
    int* rowp = (int*)alloc((N0 + 1) * 4);
    int* rowpD = (int*)alloc((N0 + 1) * 4);
    int* cursor = (int*)alloc(N0 * 4);
    int* cursorD = (int*)alloc(N0 * 4);
    int* cols = (int*)alloc((size_t)EMAX * 4);
    int* srcs = (int*)alloc((size_t)EMAX * 4);
    int* invperm = (int*)alloc(N0 * 4);
    float* dis0 = (float*)alloc(N0 * 4);
    float* fixb0 = (float*)alloc(N0 * 4);
    unsigned long long* keys = (unsigned long long*)alloc((size_t)N0 * 8);
    float* A1 = (float*)alloc((size_t)2048 * 2048 * 4);
    float* A2 = (float*)alloc((size_t)1024 * 1024 * 4);
    float* A3 = (float*)alloc((size_t)512 * 512 * 4);
    float* A4 = (float*)alloc((size_t)256 * 256 * 4);
    float* Gr = (float*)alloc((size_t)1024 * 2048 * 4);
    float* Gc = (float*)alloc((size_t)2048 * 1024 * 4);
    unsigned short* Grb = (unsigned short*)alloc((size_t)1024 * 2048 * 2);
    unsigned short* GcTb = (unsigned short*)alloc((size_t)1024 * 2048 * 2);
    float* Cpart = (float*)alloc((size_t)8 * 512 * 512 * 4);
    float* degp = (float*)alloc((size_t)32 * 2048 * 4);
    float* aggp = (float*)alloc((size_t)8 * APSTR * 4);
    float* xs0 = (float*)alloc((size_t)N0 * H * 4);
    float* xs1 = (float*)alloc((size_t)2000 * H * 4);
    float* xs2 = (float*)alloc((size_t)1000 * H * 4);
    float* xs3 = (float*)alloc((size_t)500 * H * 4);
    float* xtA = (float*)alloc((size_t)N0 * H * 4);
    float* xtB = (float*)alloc((size_t)N0 * H * 4);
    float* msgb = (float*)alloc((size_t)N0 * H * 4);
    float* dis = (float*)alloc(N0 * 4);
    float* fixb = (float*)alloc(N0 * 4);
    const int ksz[4] = {2000, 1000, 500, 250};
    int* perm[4];
    float* vals[4];
    for (int i = 0; i < 4; i++) perm[i] = (int*)alloc((size_t)ksz[i] * 4);
    for (int i = 0; i < 4; i++) vals[i] = (float*)alloc((size_t)ksz[i] * 4);

    if (off > ws_size) {
        fill_sentinel_kernel<<<(out_size + 255) / 256, 256, 0, stream>>>((float*)d_out, out_size);
        return;
    }

    const int nlvl[5] = {N0, 2000, 1000, 500, 250};
    const int ldl[5] = {N0, 2048, 1024, 512, 256};
    const int npw[4] = {4096, 2048, 1024, 512};
    float* Afp[5] = {nullptr, A1, A2, A3, A4};
    float* xsb[4] = {xs0, xs1, xs2, xs3};

    // ---- CSR build + level-0 stats ----
    hipMemsetAsync(rowcnt, 0, (size_t)N0 * 3 * 4, stream);
    build_stats_kernel<<<(E + 255) / 256, 256, 0, stream>>>(eidx, E, rowcnt, rowcntD, diagcnt);
    scan2_kernel<<<1, 1024, 0, stream>>>(rowcnt, rowp, cursor, rowcntD, rowpD, cursorD);
    fill_csr_kernel<<<(E + 255) / 256, 256, 0, stream>>>(eidx, E, cursor, cols, cursorD, srcs);

    // ---- GCN level 0 (sparse, 3->32, relu); degfin fused into msg0 ----
    msg0_kernel<<<(N0 * H + 255) / 256, 256, 0, stream>>>(x0f, W0f, rowcntD, diagcnt, dis0, fixb0,
                                                          msgb, N0);
    cscagg_epi_kernel<H><<<(N0 * H + 255) / 256, 256, 0, stream>>>(rowpD, srcs, msgb, dis0, fixb0,
                                                                   b0f, xs0, N0, 1);
    float* xcur = xs0;

    // ---- down path ----
    for (int i = 0; i < 4; ++i) {
        int nd = nlvl[i], kk = ksz[i], ldn = ldl[i + 1];
        score_keys_kernel<<<(npw[i] + 255) / 256, 256, 0, stream>>>(xcur, Pf + i * H, nd, npw[i], keys);
        topk_rank_kernel<<<npw[i] / 16, 256, 0, stream>>>(keys, npw[i], kk, perm[i], vals[i]);
        if (i == 0) {
            hipMemsetAsync(invperm, 0xFF, (size_t)N0 * 4, stream);
            invperm_set_kernel<<<(kk + 255) / 256, 256, 0, stream>>>(perm[0], invperm, kk);
            aug0_kernel<<<ldn, 256, 0, stream>>>(rowp, cols, perm[0], invperm, kk, ldn, A1);
        } else if (i == 1) {
            int ldM = ldl[i];
            dim3 gr((ldM + 255) / 256, ldn);
            gather_rows_bf16_kernel<<<gr, 256, 0, stream>>>(Afp[i], ldM, perm[i], kk, Grb);
            dim3 gt(ldn / 32, ldM / 32);
            gather_colsT_bf16_kernel<<<gt, dim3(32, 8), 0, stream>>>(Afp[i], ldM, perm[i], kk, GcTb);
            hipMemsetAsync(Afp[i + 1], 0, (size_t)ldn * ldn * 4, stream);
            int ksplit = 4;
            int kchunk = ldM / ksplit;
            dim3 gg(ldn / 64, ldn / 64, ksplit);
            mfma_aug_kernel<<<gg, 256, 0, stream>>>(Grb, GcTb, Afp[i + 1], ldM, ldn, kchunk);
        } else {
            int ldM = ldl[i];
            dim3 gr((ldM + 255) / 256, ldn);
            gather_rows_kernel<<<gr, 256, 0, stream>>>(Afp[i], ldM, perm[i], kk, Gr);
            dim3 gc((ldn + 255) / 256, ldM);
            gather_cols_kernel<<<gc, 256, 0, stream>>>(Afp[i], ldM, perm[i], kk, Gc, ldn);
            int ksplit = 8;
            int kchunk = ldM / ksplit;
            dim3 gg(ldn / 64, ldn / 64, ksplit);
            gemm64_kernel<<<gg, 256, 0, stream>>>(Gr, Gc, Cpart, ldM, ldn, kchunk);
            long tot = (long)ldn * ldn;
            reduce_part_kernel<<<(tot + 255) / 256, 256, 0, stream>>>(Cpart, Afp[i + 1], ldn, ksplit);
        }
        float* outx = (i < 3) ? xsb[i + 1] : xtB;
        run_gcn_dense(stream, Afp[i + 1], kk, ldn, xcur, perm[i], vals[i], Wdf + i * (H * H),
                      bdf + i * H, 1, outx, degp, aggp, dis, fixb, msgb);
        xcur = outx;
    }

    // ---- up path ----
    for (int i = 0; i < 4; ++i) {
        int j = 3 - i;
        int nj = nlvl[j], kj = ksz[j];
        copy_kernel<<<(nj * H + 255) / 256, 256, 0, stream>>>(xtA, xsb[j], nj * H);
        scatter_add_kernel<<<(kj * H + 255) / 256, 256, 0, stream>>>(xtA, xcur, perm[j], kj);
        if (i < 3) {
            run_gcn_dense(stream, Afp[j], nj, ldl[j], xtA, nullptr, nullptr, Wuf + i * (H * H),
                          buf2 + i * H, 1, xtB, degp, aggp, dis, fixb, msgb);
        } else {
            msg_kernel<H, 3><<<(N0 * 3 + 255) / 256, 256, 0, stream>>>(xtA, Wlf, dis0, msgb, N0);
            cscagg_lsm_kernel<<<(N0 + 255) / 256, 256, 0, stream>>>(rowpD, srcs, msgb, dis0, fixb0,
                                                                    blf, (float*)d_out, N0);
        }
        xcur = xtB;
    }
}

// Round 20
// 446.036 us; speedup vs baseline: 1.2528x; 1.0705x over previous
//
#include <hip/hip_runtime.h>
#include <math.h>

#define H 32
#define N0 4096
#define EMAX 131072
#define APSTR (4096 * 32)

typedef __attribute__((ext_vector_type(4))) float floatx4;
typedef __attribute__((ext_vector_type(8))) short short8;

__device__ __forceinline__ unsigned short f2bf_bits(float v) {
    union { float f; unsigned u; } c;
    c.f = v;
    unsigned lsb = (c.u >> 16) & 1u;
    c.u += 0x7fffu + lsb;   // RNE; inputs here are small exact integers
    return (unsigned short)(c.u >> 16);
}

// ---------------- sentinel ----------------
__global__ void fill_sentinel_kernel(float* out, int n) {
    int t = blockIdx.x * 256 + threadIdx.x;
    if (t < n) out[t] = 9.0f;
}

// ---------------- CSR build ----------------
__global__ void build_stats_kernel(const int* __restrict__ ei, int E, int* __restrict__ rowcnt,
                                   int* __restrict__ rowcntD, int* __restrict__ diagcnt) {
    int t = blockIdx.x * 256 + threadIdx.x;
    if (t >= E) return;
    int s = ei[t], d = ei[E + t];
    if ((unsigned)s >= N0 || (unsigned)d >= N0) return;
    atomicAdd(&rowcnt[s], 1);
    atomicAdd(&rowcntD[d], 1);
    if (s == d) atomicAdd(&diagcnt[s], 1);
}

// both scans + cursor copies in one launch
__global__ __launch_bounds__(1024) void scan2_kernel(const int* __restrict__ cntA, int* __restrict__ rowpA,
                                                     int* __restrict__ curA, const int* __restrict__ cntB,
                                                     int* __restrict__ rowpB, int* __restrict__ curB) {
    __shared__ int part[1024];
    int tid = threadIdx.x;
    for (int pass = 0; pass < 2; pass++) {
        const int* cnt = pass ? cntB : cntA;
        int* rowp = pass ? rowpB : rowpA;
        int* cur = pass ? curB : curA;
        int base = tid * 4;
        int local[4];
        int s = 0;
#pragma unroll
        for (int i = 0; i < 4; i++) { local[i] = s; s += cnt[base + i]; }
        part[tid] = s;
        __syncthreads();
        for (int off = 1; off < 1024; off <<= 1) {
            int v = (tid >= off) ? part[tid - off] : 0;
            __syncthreads();
            part[tid] += v;
            __syncthreads();
        }
        int pre = (tid == 0) ? 0 : part[tid - 1];
#pragma unroll
        for (int i = 0; i < 4; i++) { rowp[base + i] = pre + local[i]; cur[base + i] = pre + local[i]; }
        if (tid == 1023) rowp[N0] = pre + s;
        __syncthreads();
    }
}

__global__ void fill_csr_kernel(const int* __restrict__ ei, int E, int* __restrict__ cursor,
                                int* __restrict__ cols, int* __restrict__ cursorD,
                                int* __restrict__ srcs) {
    int t = blockIdx.x * 256 + threadIdx.x;
    if (t >= E) return;
    int s = ei[t], d = ei[E + t];
    if ((unsigned)s >= N0 || (unsigned)d >= N0) return;
    int pos = atomicAdd(&cursor[s], 1);
    cols[pos] = d;
    int posD = atomicAdd(&cursorD[d], 1);
    srcs[posD] = s;
}

__global__ void invperm_set_kernel(const int* __restrict__ perm, int* __restrict__ invperm, int k) {
    int t = blockIdx.x * 256 + threadIdx.x;
    if (t < k) invperm[perm[t]] = t;
}

// ---------------- level-0 fused augment+pool ----------------
__global__ __launch_bounds__(256) void aug0_kernel(const int* __restrict__ rowp, const int* __restrict__ cols,
                                                   const int* __restrict__ perm, const int* __restrict__ invperm,
                                                   int kOut, int ldC, float* __restrict__ C) {
    __shared__ float row[2048];
    int a = blockIdx.x;
    int tid = threadIdx.x;
    for (int j = tid; j < ldC; j += 256) row[j] = 0.f;
    __syncthreads();
    if (a < kOut) {
        int pa = perm[a];
        int s0 = rowp[pa], s1 = rowp[pa + 1];
        for (int e = s0 + tid; e < s1; e += 256) {
            int k = cols[e];
            int ip = invperm[k];
            if (ip >= 0) atomicAdd(&row[ip], 2.0f);
            int t1 = rowp[k + 1];
            for (int e2 = rowp[k]; e2 < t1; ++e2) {
                int ip2 = invperm[cols[e2]];
                if (ip2 >= 0) atomicAdd(&row[ip2], 1.0f);
            }
        }
    }
    __syncthreads();
    for (int j = tid; j < ldC; j += 256) C[(long)a * ldC + j] = (j == a) ? 0.f : row[j];
}

// ---------------- deeper levels: pre-gathered operands + GEMM ----------------
__global__ void gather_rows_kernel(const float* __restrict__ M, int ldM, const int* __restrict__ perm,
                                   int kOut, float* __restrict__ Gr) {
    int k = blockIdx.x * 256 + threadIdx.x;
    int a = blockIdx.y;
    if (k >= ldM) return;
    float v = 0.f;
    if (a < kOut) {
        int pa = perm[a];
        v = M[(long)pa * ldM + k] + (k == pa ? 1.f : 0.f);
    }
    Gr[(long)a * ldM + k] = v;
}

__global__ void gather_rows_bf16_kernel(const float* __restrict__ M, int ldM, const int* __restrict__ perm,
                                        int kOut, unsigned short* __restrict__ Gr) {
    int k = blockIdx.x * 256 + threadIdx.x;
    int a = blockIdx.y;
    if (k >= ldM) return;
    float v = 0.f;
    if (a < kOut) {
        int pa = perm[a];
        v = M[(long)pa * ldM + k] + (k == pa ? 1.f : 0.f);
    }
    Gr[(long)a * ldM + k] = f2bf_bits(v);
}

__global__ void gather_cols_kernel(const float* __restrict__ M, int ldM, const int* __restrict__ perm,
                                   int kOut, float* __restrict__ Gc, int ldC) {
    int b = blockIdx.x * 256 + threadIdx.x;
    int k = blockIdx.y;
    if (b >= ldC) return;
    float v = 0.f;
    if (b < kOut) {
        int pb = perm[b];
        v = M[(long)k * ldM + pb] + (k == pb ? 1.f : 0.f);
    }
    Gc[(long)k * ldC + b] = v;
}

// fused gather+transpose+cvt: GcT[b][k] = bf16((M+I)[k, perm[b]]). Grid (ldn/32, ldM/32), block (32,8)
__global__ void gather_colsT_bf16_kernel(const float* __restrict__ M, int ldM,
                                         const int* __restrict__ perm, int kOut,
                                         unsigned short* __restrict__ GcT) {
    __shared__ float t[32][33];
    __shared__ int pb[32];
    int b0 = blockIdx.x * 32, k0 = blockIdx.y * 32;
    int tx = threadIdx.x, ty = threadIdx.y;
    if (ty == 0) pb[tx] = (b0 + tx < kOut) ? perm[b0 + tx] : -1;
    __syncthreads();
    for (int y = ty; y < 32; y += 8) {
        int k = k0 + y;
        int pbx = pb[tx];
        float v = 0.f;
        if (pbx >= 0) v = M[(long)k * ldM + pbx] + (k == pbx ? 1.f : 0.f);
        t[y][tx] = v;
    }
    __syncthreads();
    for (int y = ty; y < 32; y += 8)
        GcT[(long)(b0 + y) * ldM + k0 + tx] = f2bf_bits(t[tx][y]);
}

__global__ __launch_bounds__(256) void mfma_aug_kernel(const unsigned short* __restrict__ Aop,
                                                       const unsigned short* __restrict__ Bop,
                                                       float* __restrict__ C, int K, int ldC, int kchunk) {
    __shared__ __align__(16) unsigned short lA[64 * 32];
    __shared__ __align__(16) unsigned short lB[64 * 32];
    const int tid = threadIdx.x;
    const int lane = tid & 63;
    const int w = tid >> 6;
    const int a0 = blockIdx.y * 64, b0 = blockIdx.x * 64;
    const int kbase = blockIdx.z * kchunk;
    const int r0 = tid >> 2;
    const int c8 = (tid & 3) * 8;
    const unsigned short* gA = Aop + (long)(a0 + r0) * K + kbase + c8;
    const unsigned short* gB = Bop + (long)(b0 + r0) * K + kbase + c8;
    const int wm = (w & 1) * 32;
    const int wn = (w >> 1) * 32;
    const int lm = lane & 15;
    const int quad = lane >> 4;
    floatx4 acc[2][2];
#pragma unroll
    for (int i = 0; i < 2; i++)
#pragma unroll
        for (int j = 0; j < 2; j++) {
            floatx4 z = {0.f, 0.f, 0.f, 0.f};
            acc[i][j] = z;
        }
    for (int k0 = 0; k0 < kchunk; k0 += 32) {
        short8 va = *(const short8*)(gA + k0);
        short8 vb = *(const short8*)(gB + k0);
        __syncthreads();
        *(short8*)&lA[r0 * 32 + c8] = va;
        *(short8*)&lB[r0 * 32 + c8] = vb;
        __syncthreads();
        short8 af[2], bf[2];
#pragma unroll
        for (int mi = 0; mi < 2; mi++) af[mi] = *(const short8*)&lA[(wm + mi * 16 + lm) * 32 + quad * 8];
#pragma unroll
        for (int ni = 0; ni < 2; ni++) bf[ni] = *(const short8*)&lB[(wn + ni * 16 + lm) * 32 + quad * 8];
#pragma unroll
        for (int mi = 0; mi < 2; mi++)
#pragma unroll
            for (int ni = 0; ni < 2; ni++)
                acc[mi][ni] = __builtin_amdgcn_mfma_f32_16x16x32_bf16(af[mi], bf[ni], acc[mi][ni], 0, 0, 0);
    }
#pragma unroll
    for (int mi = 0; mi < 2; mi++)
#pragma unroll
        for (int ni = 0; ni < 2; ni++) {
            int col = b0 + wn + ni * 16 + lm;
#pragma unroll
            for (int r = 0; r < 4; r++) {
                int row = a0 + wm + mi * 16 + quad * 4 + r;
                if (row != col) atomicAdd(&C[(long)row * ldC + col], acc[mi][ni][r]);
            }
        }
}

__global__ __launch_bounds__(256) void gemm64_kernel(const float* __restrict__ Gr,
                                                     const float* __restrict__ Gc,
                                                     float* __restrict__ Cpart, int K, int ldC, int kchunk) {
    __shared__ float As[32][68];
    __shared__ float Bs[32][68];
    const int tid = threadIdx.x;
    const int a0 = blockIdx.y * 64, b0 = blockIdx.x * 64;
    const int kbase = blockIdx.z * kchunk;
    float* Cz = Cpart + (long)blockIdx.z * ldC * ldC;
    const int tx = tid & 15, ty = tid >> 4;
    const int lr = tid >> 2;
    const int lk = (tid & 3) * 8;
    const int bb = tid & 63;
    const int kr = (tid >> 6) * 8;
    const float* gA = Gr + (long)(a0 + lr) * K + lk + kbase;
    const float* gB = Gc + (long)(kr + kbase) * ldC + b0 + bb;
    float acc[4][4];
#pragma unroll
    for (int i = 0; i < 4; i++)
#pragma unroll
        for (int j = 0; j < 4; j++) acc[i][j] = 0.f;
    for (int k0 = 0; k0 < kchunk; k0 += 32) {
        float a8[8], b8[8];
#pragma unroll
        for (int i = 0; i < 8; i++) a8[i] = gA[k0 + i];
#pragma unroll
        for (int i = 0; i < 8; i++) b8[i] = gB[(long)(k0 + i) * ldC];
        __syncthreads();
#pragma unroll
        for (int i = 0; i < 8; i++) As[lk + i][lr] = a8[i];
#pragma unroll
        for (int i = 0; i < 8; i++) Bs[kr + i][bb] = b8[i];
        __syncthreads();
#pragma unroll
        for (int k = 0; k < 32; k++) {
            floatx4 av = *(const floatx4*)&As[k][ty * 4];
            floatx4 bv = *(const floatx4*)&Bs[k][tx * 4];
#pragma unroll
            for (int i = 0; i < 4; i++)
#pragma unroll
                for (int j = 0; j < 4; j++) acc[i][j] += av[i] * bv[j];
        }
    }
#pragma unroll
    for (int i = 0; i < 4; i++)
#pragma unroll
        for (int j = 0; j < 4; j++) {
            int a = a0 + ty * 4 + i, b = b0 + tx * 4 + j;
            Cz[(long)a * ldC + b] = acc[i][j];
        }
}

__global__ void reduce_part_kernel(const float* __restrict__ Cpart, float* __restrict__ C,
                                   int ldC, int ksplit) {
    int t = blockIdx.x * 256 + threadIdx.x;
    long tot = (long)ldC * ldC;
    if (t >= tot) return;
    float s = 0.f;
    for (int z = 0; z < ksplit; z++) s += Cpart[(long)z * tot + t];
    int a = t / ldC, b = t % ldC;
    C[t] = (a == b) ? 0.f : s;
}

// ---------------- GCN (dense levels): partial-sum pipeline ----------------
__global__ void colsum_part_kernel(const float* __restrict__ A, float* __restrict__ degp, int ld) {
    int i = blockIdx.x * 256 + threadIdx.x;
    int jb = blockIdx.y;
    int j0 = jb * 64;
    float s0 = 0.f, s1 = 0.f, s2 = 0.f, s3 = 0.f, s4 = 0.f, s5 = 0.f, s6 = 0.f, s7 = 0.f;
    const float* p = A + (long)j0 * ld + i;
#pragma unroll
    for (int jq = 0; jq < 64; jq += 8) {
        float v[8];
#pragma unroll
        for (int q = 0; q < 8; q++) v[q] = p[(long)(jq + q) * ld];
        s0 += v[0]; s1 += v[1]; s2 += v[2]; s3 += v[3];
        s4 += v[4]; s5 += v[5]; s6 += v[6]; s7 += v[7];
    }
    float s = ((s0 + s1) + (s2 + s3)) + ((s4 + s5) + (s6 + s7));
    degp[(long)jb * ld + i] = s;
}

// msg + (optional) degree finalize. degp==null: read precomputed dis/fixb (up path).
__global__ void msgg_kernel(const float* __restrict__ x, const int* __restrict__ perm,
                            const float* __restrict__ vals, const float* __restrict__ Wb,
                            const float* __restrict__ A, int ld, const float* __restrict__ degp,
                            int nparts, float* __restrict__ dis, float* __restrict__ fixb,
                            float* __restrict__ msg, int n) {
    int idx = blockIdx.x * 256 + threadIdx.x;
    if (idx >= n * 32) return;
    int i = idx >> 5, c = idx & 31;
    float di, fx;
    if (degp) {
        float dsum = 0.f;
        for (int z = 0; z < nparts; z++) dsum += degp[(long)z * ld + i];
        float diag = A[(long)i * ld + i];
        fx = diag > 0.f ? 0.f : 2.f;
        float dg = dsum + fx;
        di = dg > 0.f ? 1.f / sqrtf(dg) : 0.f;
        if (c == 0) { dis[i] = di; fixb[i] = fx; }
    } else {
        di = dis[i];
        fx = fixb[i];
    }
    int src = perm ? perm[i] : i;
    float vs = vals ? vals[i] : 1.f;
    float s = 0.f;
#pragma unroll
    for (int q = 0; q < 32; q++) s += x[src * 32 + q] * Wb[q * 32 + c];
    msg[idx] = s * vs * di;
    (void)fx;
}

__global__ __launch_bounds__(256) void aggT_kernel(const float* __restrict__ A,
                                                   const float* __restrict__ msg,
                                                   float* __restrict__ aggp, int n, int ld, int jchunk) {
    __shared__ float As[64][64];
    __shared__ float Ms[64][32];
    const int tid = threadIdx.x;
    const int i0 = blockIdx.x * 64;
    const int il = tid & 63;
    const int cg = tid >> 6;
    const int i = i0 + il;
    const int mrow = tid >> 2;
    const int mc = (tid & 3) * 8;
    float acc[8];
#pragma unroll
    for (int q = 0; q < 8; q++) acc[q] = 0.f;
    const int j0 = blockIdx.y * jchunk;
    for (int jb = j0; jb < j0 + jchunk; jb += 64) {
        float a16[16], m8[8];
#pragma unroll
        for (int q = 0; q < 16; q++) a16[q] = A[(long)(jb + cg + 4 * q) * ld + i0 + il];
#pragma unroll
        for (int q = 0; q < 8; q++) m8[q] = msg[(long)(jb + mrow) * 32 + mc + q];
        __syncthreads();
#pragma unroll
        for (int q = 0; q < 16; q++) As[cg + 4 * q][il] = a16[q];
#pragma unroll
        for (int q = 0; q < 8; q++) Ms[mrow][mc + q] = m8[q];
        __syncthreads();
#pragma unroll
        for (int jl = 0; jl < 64; jl++) {
            float a = As[jl][il];
#pragma unroll
            for (int q = 0; q < 8; q++) acc[q] += a * Ms[jl][cg * 8 + q];
        }
        __syncthreads();
    }
    if (i < n) {
#pragma unroll
        for (int q = 0; q < 8; q++) aggp[(long)blockIdx.y * APSTR + (long)i * 32 + cg * 8 + q] = acc[q];
    }
}

// epilogue; if p!=null also emits next-level pooling keys via 32-lane wave reduction
// (full n*32 / npow*32 thread parallelism preserved — NOT the r18 serial-loop mistake)
__global__ void epi_sum_kernel(const float* __restrict__ aggp, int jsplit, const float* __restrict__ msg,
                               const float* __restrict__ dis, const float* __restrict__ fixb,
                               const float* __restrict__ bb, float* __restrict__ out, int n, int relu,
                               const float* __restrict__ p, int npow,
                               unsigned long long* __restrict__ keys) {
    __shared__ float psh[32];
    if (p) {
        if (threadIdx.x < 32) psh[threadIdx.x] = p[threadIdx.x];
        __syncthreads();
    }
    int idx = blockIdx.x * 256 + threadIdx.x;
    int tot = (p ? npow : n) * 32;
    if (idx >= tot) return;
    int i = idx >> 5, c = idx & 31;
    float v = 0.f;
    if (i < n) {
        float s = 0.f;
        for (int z = 0; z < jsplit; z++) s += aggp[(long)z * APSTR + idx];
        v = (s + fixb[i] * msg[idx]) * dis[i] + bb[c];
        if (relu) v = fmaxf(v, 0.f);
        out[idx] = v;
    }
    if (p) {
        float pc = psh[c];
        float d = v * pc;
        float nq = pc * pc;
#pragma unroll
        for (int st = 16; st >= 1; st >>= 1) {
            d += __shfl_xor(d, st);
            nq += __shfl_xor(nq, st);
        }
        if (c == 0) {
            unsigned long long kk = 0ULL;
            if (i < n) {
                float sc = tanhf(d / sqrtf(nq));
                unsigned u = __float_as_uint(sc);
                u = (u & 0x80000000u) ? ~u : (u | 0x80000000u);
                kk = ((unsigned long long)u << 32) | (unsigned)(~i);
            }
            keys[i] = kk;
        }
    }
}

// level-0 msg with inline degree finalize
__global__ void msg0_kernel(const float* __restrict__ x, const float* __restrict__ Wb,
                            const int* __restrict__ rowcntD, const int* __restrict__ diagcnt,
                            float* __restrict__ dis, float* __restrict__ fixb,
                            float* __restrict__ msg, int n) {
    int idx = blockIdx.x * 256 + threadIdx.x;
    if (idx >= n * 32) return;
    int i = idx >> 5, c = idx & 31;
    float fx = diagcnt[i] > 0 ? 0.f : 2.f;
    float dg = (float)rowcntD[i] + fx;
    float di = dg > 0.f ? 1.f / sqrtf(dg) : 0.f;
    if (c == 0) { dis[i] = di; fixb[i] = fx; }
    float s = x[i * 3] * Wb[c] + x[i * 3 + 1] * Wb[32 + c] + x[i * 3 + 2] * Wb[64 + c];
    msg[idx] = s * di;
}

template <int CIN, int COUT>
__global__ void msg_kernel(const float* __restrict__ x, const float* __restrict__ Wb,
                           const float* __restrict__ dis, float* __restrict__ msg, int n) {
    int idx = blockIdx.x * 256 + threadIdx.x;
    if (idx >= n * COUT) return;
    int i = idx / COUT, c = idx % COUT;
    float s = 0.f;
#pragma unroll
    for (int q = 0; q < CIN; q++) s += x[i * CIN + q] * Wb[q * COUT + c];
    msg[idx] = s * dis[i];
}

// level-0 sparse agg + epilogue + level-0 pooling keys (wave-reduced)
__global__ void cscagg_epi_keys_kernel(const int* __restrict__ rowpD, const int* __restrict__ srcs,
                                       const float* __restrict__ msg, const float* __restrict__ dis,
                                       const float* __restrict__ fixb, const float* __restrict__ bb,
                                       float* __restrict__ out, int n, const float* __restrict__ p,
                                       unsigned long long* __restrict__ keys) {
    __shared__ float psh[32];
    if (threadIdx.x < 32) psh[threadIdx.x] = p[threadIdx.x];
    __syncthreads();
    int idx = blockIdx.x * 256 + threadIdx.x;
    if (idx >= n * 32) return;
    int i = idx >> 5, c = idx & 31;
    float acc = 0.f;
    int e0 = rowpD[i], e1 = rowpD[i + 1];
    for (int e = e0; e < e1; e++) acc += msg[(long)srcs[e] * 32 + c];
    float v = (acc + fixb[i] * msg[idx]) * dis[i] + bb[c];
    v = fmaxf(v, 0.f);
    out[idx] = v;
    float pc = psh[c];
    float d = v * pc;
    float nq = pc * pc;
#pragma unroll
    for (int st = 16; st >= 1; st >>= 1) {
        d += __shfl_xor(d, st);
        nq += __shfl_xor(nq, st);
    }
    if (c == 0) {
        float sc = tanhf(d / sqrtf(nq));
        unsigned u = __float_as_uint(sc);
        u = (u & 0x80000000u) ? ~u : (u | 0x80000000u);
        keys[i] = ((unsigned long long)u << 32) | (unsigned)(~i);
    }
}

// final sparse GCN epilogue + log_softmax fused, writes d_out directly
__global__ void cscagg_lsm_kernel(const int* __restrict__ rowpD, const int* __restrict__ srcs,
                                  const float* __restrict__ msg, const float* __restrict__ dis,
                                  const float* __restrict__ fixb, const float* __restrict__ bb,
                                  float* __restrict__ out, int n) {
    int i = blockIdx.x * 256 + threadIdx.x;
    if (i >= n) return;
    float a0 = 0.f, a1 = 0.f, a2 = 0.f;
    int e0 = rowpD[i], e1 = rowpD[i + 1];
    for (int e = e0; e < e1; e++) {
        const float* m = &msg[(long)srcs[e] * 3];
        a0 += m[0]; a1 += m[1]; a2 += m[2];
    }
    float di = dis[i], fx = fixb[i];
    float v0 = (a0 + fx * msg[i * 3]) * di + bb[0];
    float v1 = (a1 + fx * msg[i * 3 + 1]) * di + bb[1];
    float v2 = (a2 + fx * msg[i * 3 + 2]) * di + bb[2];
    float m = fmaxf(v0, fmaxf(v1, v2));
    float s = expf(v0 - m) + expf(v1 - m) + expf(v2 - m);
    float l = m + logf(s);
    out[i * 3] = v0 - l;
    out[i * 3 + 1] = v1 - l;
    out[i * 3 + 2] = v2 - l;
}

// rank(i)=#{j: key_j>key_i}. 2-D: block = 16 my-keys x 16 j-chunks; grid = npow/16 blocks.
__global__ __launch_bounds__(256) void topk_rank_kernel(const unsigned long long* __restrict__ keys,
                                                        int npow, int k, int* __restrict__ perm,
                                                        float* __restrict__ vals) {
    __shared__ unsigned long long ks[4096];
    __shared__ int psum[256];
    const int tid = threadIdx.x;
    for (int t = tid; t < npow; t += 256) ks[t] = keys[t];
    __syncthreads();
    const int m = tid & 15;
    const int chunk = tid >> 4;
    const int myi = blockIdx.x * 16 + m;
    unsigned long long my = ks[myi];
    const int cl = npow >> 4;
    const unsigned long long* base = &ks[chunk * cl];
    int r = 0;
#pragma unroll 4
    for (int j = 0; j < cl; j++) r += (base[j] > my) ? 1 : 0;
    psum[chunk * 16 + m] = r;
    __syncthreads();
    if (tid < 16) {
        int mk_i = blockIdx.x * 16 + tid;
        unsigned long long mk = ks[mk_i];
        int rank = 0;
#pragma unroll
        for (int c = 0; c < 16; c++) rank += psum[c * 16 + tid];
        if (rank < k) {
            perm[rank] = (int)(~(unsigned)mk);
            unsigned u = (unsigned)(mk >> 32);
            u = (u & 0x80000000u) ? (u ^ 0x80000000u) : ~u;
            vals[rank] = __uint_as_float(u);
        }
    }
}

__global__ void copy_kernel(float* __restrict__ dst, const float* __restrict__ src, int n) {
    int t = blockIdx.x * 256 + threadIdx.x;
    if (t < n) dst[t] = src[t];
}

__global__ void scatter_add_kernel(float* __restrict__ dst, const float* __restrict__ src,
                                   const int* __restrict__ perm, int k) {
    int t = blockIdx.x * 256 + threadIdx.x;
    if (t >= k * H) return;
    int a = t >> 5, c = t & 31;
    dst[perm[a] * H + c] += src[t];
}

// ---------------- host ----------------
static void run_gcn_dense(hipStream_t st, const float* A, int n, int ld, const float* x,
                          const int* perm, const float* vals, const float* Wt, const float* bt,
                          int relu, float* out, float* degp, float* aggp, float* dis, float* fixb,
                          float* msgb, int computeDeg, const float* pnext, int npow_next,
                          unsigned long long* keys) {
    if (computeDeg) {
        dim3 gcs(ld / 256 > 0 ? ld / 256 : 1, ld / 64);
        colsum_part_kernel<<<gcs, 256, 0, st>>>(A, degp, ld);
    }
    int gm = (n * H + 255) / 256;
    msgg_kernel<<<gm, 256, 0, st>>>(x, perm, vals, Wt, A, ld, computeDeg ? degp : nullptr, ld / 64,
                                    dis, fixb, msgb, n);
    int jsplit = ld / 256 > 0 ? ld / 256 : 1;
    int ajc = ld / jsplit;
    dim3 ga(ld / 64, jsplit);
    aggT_kernel<<<ga, 256, 0, st>>>(A, msgb, aggp, n, ld, ajc);
    int gme = ((pnext ? npow_next : n) * H + 255) / 256;
    epi_sum_kernel<<<gme, 256, 0, st>>>(aggp, jsplit, msgb, dis, fixb, bt, out, n, relu,
                                        pnext, npow_next, keys);
}

extern "C" void kernel_launch(void* const* d_in, const int* in_sizes, int n_in,
                              void* d_out, int out_size, void* d_ws, size_t ws_size,
                              hipStream_t stream) {
    const float* x0f = (const float*)d_in[0];
    const int* eidx = (const int*)d_in[1];
    const float* W0f = (const float*)d_in[2];
    const float* b0f = (const float*)d_in[3];
    const float* Wdf = (const float*)d_in[4];
    const float* bdf = (const float*)d_in[5];
    const float* Pf = (const float*)d_in[6];
    const float* Wuf = (const float*)d_in[7];
    const float* buf2 = (const float*)d_in[8];
    const float* Wlf = (const float*)d_in[9];
    const float* blf = (const float*)d_in[10];
    const int E = in_sizes[1] / 2;

    unsigned char* w = (unsigned char*)d_ws;
    size_t off = 0;
    auto alloc = [&](size_t bytes) -> void* {
        void* p = w + off;
        off += (bytes + 255) & ~(size_t)255;
        return p;
    };
    int* rowcnt = (int*)alloc(N0 * 4);
    int* rowcntD = (int*)alloc(N0 * 4);
    int* diagcnt = (int*)alloc(N0 * 4);
    int* rowp = (int*)alloc((N0 + 1) * 4);
    int* rowpD = (int*)alloc((N0 + 1) * 4);
    int* cursor = (int*)alloc(N0 * 4);
    int* cursorD = (int*)alloc(N0 * 4);
    int* cols = (int*)alloc((size_t)EMAX * 4);
    int* srcs = (int*)alloc((size_t)EMAX * 4);
    int* invperm = (int*)alloc(N0 * 4);
    float* dis0 = (float*)alloc(N0 * 4);
    float* fixb0 = (float*)alloc(N0 * 4);
    unsigned long long* keys = (unsigned long long*)alloc((size_t)N0 * 8);
    float* A1 = (float*)alloc((size_t)2048 * 2048 * 4);
    float* A2 = (float*)alloc((size_t)1024 * 1024 * 4);
    float* A3 = (float*)alloc((size_t)512 * 512 * 4);
    float* A4 = (float*)alloc((size_t)256 * 256 * 4);
    float* Gr = (float*)alloc((size_t)1024 * 2048 * 4);
    float* Gc = (float*)alloc((size_t)2048 * 1024 * 4);
    unsigned short* Grb = (unsigned short*)alloc((size_t)1024 * 2048 * 2);
    unsigned short* GcTb = (unsigned short*)alloc((size_t)1024 * 2048 * 2);
    float* Cpart = (float*)alloc((size_t)8 * 512 * 512 * 4);
    float* degp = (float*)alloc((size_t)32 * 2048 * 4);
    float* aggp = (float*)alloc((size_t)8 * APSTR * 4);
    float* xs0 = (float*)alloc((size_t)N0 * H * 4);
    float* xs1 = (float*)alloc((size_t)2000 * H * 4);
    float* xs2 = (float*)alloc((size_t)1000 * H * 4);
    float* xs3 = (float*)alloc((size_t)500 * H * 4);
    float* xtA = (float*)alloc((size_t)N0 * H * 4);
    float* xtB = (float*)alloc((size_t)N0 * H * 4);
    float* msgb = (float*)alloc((size_t)N0 * H * 4);
    float* disL = (float*)alloc((size_t)4 * N0 * 4);   // per-level cached dis (adjacency 1..4)
    float* fixbL = (float*)alloc((size_t)4 * N0 * 4);
    const int ksz[4] = {2000, 1000, 500, 250};
    int* perm[4];
    float* vals[4];
    for (int i = 0; i < 4; i++) perm[i] = (int*)alloc((size_t)ksz[i] * 4);
    for (int i = 0; i < 4; i++) vals[i] = (float*)alloc((size_t)ksz[i] * 4);

    if (off > ws_size) {
        fill_sentinel_kernel<<<(out_size + 255) / 256, 256, 0, stream>>>((float*)d_out, out_size);
        return;
    }

    const int nlvl[5] = {N0, 2000, 1000, 500, 250};
    const int ldl[5] = {N0, 2048, 1024, 512, 256};
    const int npw[4] = {4096, 2048, 1024, 512};
    float* Afp[5] = {nullptr, A1, A2, A3, A4};
    float* xsb[4] = {xs0, xs1, xs2, xs3};

    // ---- CSR build + level-0 stats ----
    hipMemsetAsync(rowcnt, 0, (size_t)N0 * 3 * 4, stream);
    build_stats_kernel<<<(E + 255) / 256, 256, 0, stream>>>(eidx, E, rowcnt, rowcntD, diagcnt);
    scan2_kernel<<<1, 1024, 0, stream>>>(rowcnt, rowp, cursor, rowcntD, rowpD, cursorD);
    fill_csr_kernel<<<(E + 255) / 256, 256, 0, stream>>>(eidx, E, cursor, cols, cursorD, srcs);

    // ---- GCN level 0 (sparse, 3->32, relu) + level-0 pooling keys ----
    msg0_kernel<<<(N0 * H + 255) / 256, 256, 0, stream>>>(x0f, W0f, rowcntD, diagcnt, dis0, fixb0,
                                                          msgb, N0);
    cscagg_epi_keys_kernel<<<(N0 * H + 255) / 256, 256, 0, stream>>>(rowpD, srcs, msgb, dis0, fixb0,
                                                                     b0f, xs0, N0, Pf, keys);
    float* xcur = xs0;

    // ---- down path ----
    for (int i = 0; i < 4; ++i) {
        int kk = ksz[i], ldn = ldl[i + 1];
        // keys for level i were produced by the previous epilogue (cscagg_epi_keys or epi_sum)
        topk_rank_kernel<<<npw[i] / 16, 256, 0, stream>>>(keys, npw[i], kk, perm[i], vals[i]);
        if (i == 0) {
            hipMemsetAsync(invperm, 0xFF, (size_t)N0 * 4, stream);
            invperm_set_kernel<<<(kk + 255) / 256, 256, 0, stream>>>(perm[0], invperm, kk);
            aug0_kernel<<<ldn, 256, 0, stream>>>(rowp, cols, perm[0], invperm, kk, ldn, A1);
        } else if (i == 1) {
            int ldM = ldl[i];
            dim3 gr((ldM + 255) / 256, ldn);
            gather_rows_bf16_kernel<<<gr, 256, 0, stream>>>(Afp[i], ldM, perm[i], kk, Grb);
            dim3 gt(ldn / 32, ldM / 32);
            gather_colsT_bf16_kernel<<<gt, dim3(32, 8), 0, stream>>>(Afp[i], ldM, perm[i], kk, GcTb);
            hipMemsetAsync(Afp[i + 1], 0, (size_t)ldn * ldn * 4, stream);
            int ksplit = 4;
            int kchunk = ldM / ksplit;
            dim3 gg(ldn / 64, ldn / 64, ksplit);
            mfma_aug_kernel<<<gg, 256, 0, stream>>>(Grb, GcTb, Afp[i + 1], ldM, ldn, kchunk);
        } else {
            int ldM = ldl[i];
            dim3 gr((ldM + 255) / 256, ldn);
            gather_rows_kernel<<<gr, 256, 0, stream>>>(Afp[i], ldM, perm[i], kk, Gr);
            dim3 gc((ldn + 255) / 256, ldM);
            gather_cols_kernel<<<gc, 256, 0, stream>>>(Afp[i], ldM, perm[i], kk, Gc, ldn);
            int ksplit = 8;
            int kchunk = ldM / ksplit;
            dim3 gg(ldn / 64, ldn / 64, ksplit);
            gemm64_kernel<<<gg, 256, 0, stream>>>(Gr, Gc, Cpart, ldM, ldn, kchunk);
            long tot = (long)ldn * ldn;
            reduce_part_kernel<<<(tot + 255) / 256, 256, 0, stream>>>(Cpart, Afp[i + 1], ldn, ksplit);
        }
        float* outx = (i < 3) ? xsb[i + 1] : xtB;
        const float* pnext = (i < 3) ? (Pf + (i + 1) * H) : nullptr;
        int npow_next = (i < 3) ? npw[i + 1] : 0;
        run_gcn_dense(stream, Afp[i + 1], kk, ldn, xcur, perm[i], vals[i], Wdf + i * (H * H),
                      bdf + i * H, 1, outx, degp, aggp, disL + i * N0, fixbL + i * N0, msgb,
                      1, pnext, npow_next, keys);
        xcur = outx;
    }

    // ---- up path (dis/fixb reused from down-path: same adjacency per level) ----
    for (int i = 0; i < 4; ++i) {
        int j = 3 - i;
        int nj = nlvl[j], kj = ksz[j];
        copy_kernel<<<(nj * H + 255) / 256, 256, 0, stream>>>(xtA, xsb[j], nj * H);
        scatter_add_kernel<<<(kj * H + 255) / 256, 256, 0, stream>>>(xtA, xcur, perm[j], kj);
        if (i < 3) {
            run_gcn_dense(stream, Afp[j], nj, ldl[j], xtA, nullptr, nullptr, Wuf + i * (H * H),
                          buf2 + i * H, 1, xtB, degp, aggp, disL + (j - 1) * N0,
                          fixbL + (j - 1) * N0, msgb, 0, nullptr, 0, nullptr);
        } else {
            msg_kernel<H, 3><<<(N0 * 3 + 255) / 256, 256, 0, stream>>>(xtA, Wlf, dis0, msgb, N0);
            cscagg_lsm_kernel<<<(N0 + 255) / 256, 256, 0, stream>>>(rowpD, srcs, msgb, dis0, fixb0,
                                                                    blf, (float*)d_out, N0);
        }
        xcur = xtB;
    }
}

// Round 21
// 440.490 us; speedup vs baseline: 1.2685x; 1.0126x over previous
//
#include <hip/hip_runtime.h>
#include <math.h>

#define H 32
#define N0 4096
#define EMAX 131072
#define APSTR (4096 * 32)

typedef __attribute__((ext_vector_type(4))) float floatx4;
typedef __attribute__((ext_vector_type(8))) short short8;

__device__ __forceinline__ unsigned short f2bf_bits(float v) {
    union { float f; unsigned u; } c;
    c.f = v;
    unsigned lsb = (c.u >> 16) & 1u;
    c.u += 0x7fffu + lsb;   // RNE; inputs here are small exact integers
    return (unsigned short)(c.u >> 16);
}

// ---------------- sentinel ----------------
__global__ void fill_sentinel_kernel(float* out, int n) {
    int t = blockIdx.x * 256 + threadIdx.x;
    if (t < n) out[t] = 9.0f;
}

// ---------------- CSR build ----------------
__global__ void build_stats_kernel(const int* __restrict__ ei, int E, int* __restrict__ rowcnt,
                                   int* __restrict__ rowcntD, int* __restrict__ diagcnt) {
    int t = blockIdx.x * 256 + threadIdx.x;
    if (t >= E) return;
    int s = ei[t], d = ei[E + t];
    if ((unsigned)s >= N0 || (unsigned)d >= N0) return;
    atomicAdd(&rowcnt[s], 1);
    atomicAdd(&rowcntD[d], 1);
    if (s == d) atomicAdd(&diagcnt[s], 1);
}

// both scans + cursor copies in one launch
__global__ __launch_bounds__(1024) void scan2_kernel(const int* __restrict__ cntA, int* __restrict__ rowpA,
                                                     int* __restrict__ curA, const int* __restrict__ cntB,
                                                     int* __restrict__ rowpB, int* __restrict__ curB) {
    __shared__ int part[1024];
    int tid = threadIdx.x;
    for (int pass = 0; pass < 2; pass++) {
        const int* cnt = pass ? cntB : cntA;
        int* rowp = pass ? rowpB : rowpA;
        int* cur = pass ? curB : curA;
        int base = tid * 4;
        int local[4];
        int s = 0;
#pragma unroll
        for (int i = 0; i < 4; i++) { local[i] = s; s += cnt[base + i]; }
        part[tid] = s;
        __syncthreads();
        for (int off = 1; off < 1024; off <<= 1) {
            int v = (tid >= off) ? part[tid - off] : 0;
            __syncthreads();
            part[tid] += v;
            __syncthreads();
        }
        int pre = (tid == 0) ? 0 : part[tid - 1];
#pragma unroll
        for (int i = 0; i < 4; i++) { rowp[base + i] = pre + local[i]; cur[base + i] = pre + local[i]; }
        if (tid == 1023) rowp[N0] = pre + s;
        __syncthreads();
    }
}

__global__ void fill_csr_kernel(const int* __restrict__ ei, int E, int* __restrict__ cursor,
                                int* __restrict__ cols, int* __restrict__ cursorD,
                                int* __restrict__ srcs) {
    int t = blockIdx.x * 256 + threadIdx.x;
    if (t >= E) return;
    int s = ei[t], d = ei[E + t];
    if ((unsigned)s >= N0 || (unsigned)d >= N0) return;
    int pos = atomicAdd(&cursor[s], 1);
    cols[pos] = d;
    int posD = atomicAdd(&cursorD[d], 1);
    srcs[posD] = s;
}

// ---------------- level-0 fused augment+pool ----------------
__global__ __launch_bounds__(256) void aug0_kernel(const int* __restrict__ rowp, const int* __restrict__ cols,
                                                   const int* __restrict__ perm, const int* __restrict__ invperm,
                                                   int kOut, int ldC, float* __restrict__ C) {
    __shared__ float row[2048];
    int a = blockIdx.x;
    int tid = threadIdx.x;
    for (int j = tid; j < ldC; j += 256) row[j] = 0.f;
    __syncthreads();
    if (a < kOut) {
        int pa = perm[a];
        int s0 = rowp[pa], s1 = rowp[pa + 1];
        for (int e = s0 + tid; e < s1; e += 256) {
            int k = cols[e];
            int ip = invperm[k];
            if (ip >= 0) atomicAdd(&row[ip], 2.0f);
            int t1 = rowp[k + 1];
            for (int e2 = rowp[k]; e2 < t1; ++e2) {
                int ip2 = invperm[cols[e2]];
                if (ip2 >= 0) atomicAdd(&row[ip2], 1.0f);
            }
        }
    }
    __syncthreads();
    for (int j = tid; j < ldC; j += 256) C[(long)a * ldC + j] = (j == a) ? 0.f : row[j];
}

// ---------------- deeper levels: pre-gathered operands + GEMM ----------------
__global__ void gather_rows_kernel(const float* __restrict__ M, int ldM, const int* __restrict__ perm,
                                   int kOut, float* __restrict__ Gr) {
    int k = blockIdx.x * 256 + threadIdx.x;
    int a = blockIdx.y;
    if (k >= ldM) return;
    float v = 0.f;
    if (a < kOut) {
        int pa = perm[a];
        v = M[(long)pa * ldM + k] + (k == pa ? 1.f : 0.f);
    }
    Gr[(long)a * ldM + k] = v;
}

__global__ void gather_rows_bf16_kernel(const float* __restrict__ M, int ldM, const int* __restrict__ perm,
                                        int kOut, unsigned short* __restrict__ Gr) {
    int k = blockIdx.x * 256 + threadIdx.x;
    int a = blockIdx.y;
    if (k >= ldM) return;
    float v = 0.f;
    if (a < kOut) {
        int pa = perm[a];
        v = M[(long)pa * ldM + k] + (k == pa ? 1.f : 0.f);
    }
    Gr[(long)a * ldM + k] = f2bf_bits(v);
}

__global__ void gather_cols_kernel(const float* __restrict__ M, int ldM, const int* __restrict__ perm,
                                   int kOut, float* __restrict__ Gc, int ldC) {
    int b = blockIdx.x * 256 + threadIdx.x;
    int k = blockIdx.y;
    if (b >= ldC) return;
    float v = 0.f;
    if (b < kOut) {
        int pb = perm[b];
        v = M[(long)k * ldM + pb] + (k == pb ? 1.f : 0.f);
    }
    Gc[(long)k * ldC + b] = v;
}

// fused gather+transpose+cvt: GcT[b][k] = bf16((M+I)[k, perm[b]]). Grid (ldn/32, ldM/32), block (32,8)
__global__ void gather_colsT_bf16_kernel(const float* __restrict__ M, int ldM,
                                         const int* __restrict__ perm, int kOut,
                                         unsigned short* __restrict__ GcT) {
    __shared__ float t[32][33];
    __shared__ int pb[32];
    int b0 = blockIdx.x * 32, k0 = blockIdx.y * 32;
    int tx = threadIdx.x, ty = threadIdx.y;
    if (ty == 0) pb[tx] = (b0 + tx < kOut) ? perm[b0 + tx] : -1;
    __syncthreads();
    for (int y = ty; y < 32; y += 8) {
        int k = k0 + y;
        int pbx = pb[tx];
        float v = 0.f;
        if (pbx >= 0) v = M[(long)k * ldM + pbx] + (k == pbx ? 1.f : 0.f);
        t[y][tx] = v;
    }
    __syncthreads();
    for (int y = ty; y < 32; y += 8)
        GcT[(long)(b0 + y) * ldM + k0 + tx] = f2bf_bits(t[tx][y]);
}

__global__ __launch_bounds__(256) void mfma_aug_kernel(const unsigned short* __restrict__ Aop,
                                                       const unsigned short* __restrict__ Bop,
                                                       float* __restrict__ C, int K, int ldC, int kchunk) {
    __shared__ __align__(16) unsigned short lA[64 * 32];
    __shared__ __align__(16) unsigned short lB[64 * 32];
    const int tid = threadIdx.x;
    const int lane = tid & 63;
    const int w = tid >> 6;
    const int a0 = blockIdx.y * 64, b0 = blockIdx.x * 64;
    const int kbase = blockIdx.z * kchunk;
    const int r0 = tid >> 2;
    const int c8 = (tid & 3) * 8;
    const unsigned short* gA = Aop + (long)(a0 + r0) * K + kbase + c8;
    const unsigned short* gB = Bop + (long)(b0 + r0) * K + kbase + c8;
    const int wm = (w & 1) * 32;
    const int wn = (w >> 1) * 32;
    const int lm = lane & 15;
    const int quad = lane >> 4;
    floatx4 acc[2][2];
#pragma unroll
    for (int i = 0; i < 2; i++)
#pragma unroll
        for (int j = 0; j < 2; j++) {
            floatx4 z = {0.f, 0.f, 0.f, 0.f};
            acc[i][j] = z;
        }
    for (int k0 = 0; k0 < kchunk; k0 += 32) {
        short8 va = *(const short8*)(gA + k0);
        short8 vb = *(const short8*)(gB + k0);
        __syncthreads();
        *(short8*)&lA[r0 * 32 + c8] = va;
        *(short8*)&lB[r0 * 32 + c8] = vb;
        __syncthreads();
        short8 af[2], bf[2];
#pragma unroll
        for (int mi = 0; mi < 2; mi++) af[mi] = *(const short8*)&lA[(wm + mi * 16 + lm) * 32 + quad * 8];
#pragma unroll
        for (int ni = 0; ni < 2; ni++) bf[ni] = *(const short8*)&lB[(wn + ni * 16 + lm) * 32 + quad * 8];
#pragma unroll
        for (int mi = 0; mi < 2; mi++)
#pragma unroll
            for (int ni = 0; ni < 2; ni++)
                acc[mi][ni] = __builtin_amdgcn_mfma_f32_16x16x32_bf16(af[mi], bf[ni], acc[mi][ni], 0, 0, 0);
    }
#pragma unroll
    for (int mi = 0; mi < 2; mi++)
#pragma unroll
        for (int ni = 0; ni < 2; ni++) {
            int col = b0 + wn + ni * 16 + lm;
#pragma unroll
            for (int r = 0; r < 4; r++) {
                int row = a0 + wm + mi * 16 + quad * 4 + r;
                if (row != col) atomicAdd(&C[(long)row * ldC + col], acc[mi][ni][r]);
            }
        }
}

__global__ __launch_bounds__(256) void gemm64_kernel(const float* __restrict__ Gr,
                                                     const float* __restrict__ Gc,
                                                     float* __restrict__ Cpart, int K, int ldC, int kchunk) {
    __shared__ float As[32][68];
    __shared__ float Bs[32][68];
    const int tid = threadIdx.x;
    const int a0 = blockIdx.y * 64, b0 = blockIdx.x * 64;
    const int kbase = blockIdx.z * kchunk;
    float* Cz = Cpart + (long)blockIdx.z * ldC * ldC;
    const int tx = tid & 15, ty = tid >> 4;
    const int lr = tid >> 2;
    const int lk = (tid & 3) * 8;
    const int bb = tid & 63;
    const int kr = (tid >> 6) * 8;
    const float* gA = Gr + (long)(a0 + lr) * K + lk + kbase;
    const float* gB = Gc + (long)(kr + kbase) * ldC + b0 + bb;
    float acc[4][4];
#pragma unroll
    for (int i = 0; i < 4; i++)
#pragma unroll
        for (int j = 0; j < 4; j++) acc[i][j] = 0.f;
    for (int k0 = 0; k0 < kchunk; k0 += 32) {
        float a8[8], b8[8];
#pragma unroll
        for (int i = 0; i < 8; i++) a8[i] = gA[k0 + i];
#pragma unroll
        for (int i = 0; i < 8; i++) b8[i] = gB[(long)(k0 + i) * ldC];
        __syncthreads();
#pragma unroll
        for (int i = 0; i < 8; i++) As[lk + i][lr] = a8[i];
#pragma unroll
        for (int i = 0; i < 8; i++) Bs[kr + i][bb] = b8[i];
        __syncthreads();
#pragma unroll
        for (int k = 0; k < 32; k++) {
            floatx4 av = *(const floatx4*)&As[k][ty * 4];
            floatx4 bv = *(const floatx4*)&Bs[k][tx * 4];
#pragma unroll
            for (int i = 0; i < 4; i++)
#pragma unroll
                for (int j = 0; j < 4; j++) acc[i][j] += av[i] * bv[j];
        }
    }
#pragma unroll
    for (int i = 0; i < 4; i++)
#pragma unroll
        for (int j = 0; j < 4; j++) {
            int a = a0 + ty * 4 + i, b = b0 + tx * 4 + j;
            Cz[(long)a * ldC + b] = acc[i][j];
        }
}

__global__ void reduce_part_kernel(const float* __restrict__ Cpart, float* __restrict__ C,
                                   int ldC, int ksplit) {
    int t = blockIdx.x * 256 + threadIdx.x;
    long tot = (long)ldC * ldC;
    if (t >= tot) return;
    float s = 0.f;
    for (int z = 0; z < ksplit; z++) s += Cpart[(long)z * tot + t];
    int a = t / ldC, b = t % ldC;
    C[t] = (a == b) ? 0.f : s;
}

// ---------------- GCN (dense levels): partial-sum pipeline ----------------
__global__ void colsum_part_kernel(const float* __restrict__ A, float* __restrict__ degp, int ld) {
    int i = blockIdx.x * 256 + threadIdx.x;
    int jb = blockIdx.y;
    int j0 = jb * 64;
    float s0 = 0.f, s1 = 0.f, s2 = 0.f, s3 = 0.f, s4 = 0.f, s5 = 0.f, s6 = 0.f, s7 = 0.f;
    const float* p = A + (long)j0 * ld + i;
#pragma unroll
    for (int jq = 0; jq < 64; jq += 8) {
        float v[8];
#pragma unroll
        for (int q = 0; q < 8; q++) v[q] = p[(long)(jq + q) * ld];
        s0 += v[0]; s1 += v[1]; s2 += v[2]; s3 += v[3];
        s4 += v[4]; s5 += v[5]; s6 += v[6]; s7 += v[7];
    }
    float s = ((s0 + s1) + (s2 + s3)) + ((s4 + s5) + (s6 + s7));
    degp[(long)jb * ld + i] = s;
}

// msg + optional degree finalize + optional pooled-gather (down) + optional fused unpool (up).
// degp!=null: compute dis/fixb from partials; else read cached dis/fixb.
// perm!=null: x-row = perm[i], scaled by vals[i] (down-path pooling gather).
// invp!=null: x-row i gets += xup[invp[i]] when invp[i]>=0 (up-path unpool, res=x).
__global__ void msgg_kernel(const float* __restrict__ x, const int* __restrict__ perm,
                            const float* __restrict__ vals, const float* __restrict__ xup,
                            const int* __restrict__ invp, const float* __restrict__ Wb,
                            const float* __restrict__ A, int ld, const float* __restrict__ degp,
                            int nparts, float* __restrict__ dis, float* __restrict__ fixb,
                            float* __restrict__ msg, int n) {
    int idx = blockIdx.x * 256 + threadIdx.x;
    if (idx >= n * 32) return;
    int i = idx >> 5, c = idx & 31;
    float di, fx;
    if (degp) {
        float dsum = 0.f;
        for (int z = 0; z < nparts; z++) dsum += degp[(long)z * ld + i];
        float diag = A[(long)i * ld + i];
        fx = diag > 0.f ? 0.f : 2.f;
        float dg = dsum + fx;
        di = dg > 0.f ? 1.f / sqrtf(dg) : 0.f;
        if (c == 0) { dis[i] = di; fixb[i] = fx; }
    } else {
        di = dis[i];
        fx = fixb[i];
    }
    int src = perm ? perm[i] : i;
    float vs = vals ? vals[i] : 1.f;
    int ip = invp ? invp[i] : -1;
    float s = 0.f;
#pragma unroll
    for (int q = 0; q < 32; q++) {
        float xv = x[(long)src * 32 + q];
        if (ip >= 0) xv += xup[(long)ip * 32 + q];
        s += xv * Wb[q * 32 + c];
    }
    msg[idx] = s * vs * di;
    (void)fx;
}

__global__ __launch_bounds__(256) void aggT_kernel(const float* __restrict__ A,
                                                   const float* __restrict__ msg,
                                                   float* __restrict__ aggp, int n, int ld, int jchunk) {
    __shared__ float As[64][64];
    __shared__ float Ms[64][32];
    const int tid = threadIdx.x;
    const int i0 = blockIdx.x * 64;
    const int il = tid & 63;
    const int cg = tid >> 6;
    const int i = i0 + il;
    const int mrow = tid >> 2;
    const int mc = (tid & 3) * 8;
    float acc[8];
#pragma unroll
    for (int q = 0; q < 8; q++) acc[q] = 0.f;
    const int j0 = blockIdx.y * jchunk;
    for (int jb = j0; jb < j0 + jchunk; jb += 64) {
        float a16[16], m8[8];
#pragma unroll
        for (int q = 0; q < 16; q++) a16[q] = A[(long)(jb + cg + 4 * q) * ld + i0 + il];
#pragma unroll
        for (int q = 0; q < 8; q++) m8[q] = msg[(long)(jb + mrow) * 32 + mc + q];
        __syncthreads();
#pragma unroll
        for (int q = 0; q < 16; q++) As[cg + 4 * q][il] = a16[q];
#pragma unroll
        for (int q = 0; q < 8; q++) Ms[mrow][mc + q] = m8[q];
        __syncthreads();
#pragma unroll
        for (int jl = 0; jl < 64; jl++) {
            float a = As[jl][il];
#pragma unroll
            for (int q = 0; q < 8; q++) acc[q] += a * Ms[jl][cg * 8 + q];
        }
        __syncthreads();
    }
    if (i < n) {
#pragma unroll
        for (int q = 0; q < 8; q++) aggp[(long)blockIdx.y * APSTR + (long)i * 32 + cg * 8 + q] = acc[q];
    }
}

// epilogue; if p!=null also emits next-level pooling keys via 32-lane wave reduction
__global__ void epi_sum_kernel(const float* __restrict__ aggp, int jsplit, const float* __restrict__ msg,
                               const float* __restrict__ dis, const float* __restrict__ fixb,
                               const float* __restrict__ bb, float* __restrict__ out, int n, int relu,
                               const float* __restrict__ p, int npow,
                               unsigned long long* __restrict__ keys) {
    __shared__ float psh[32];
    if (p) {
        if (threadIdx.x < 32) psh[threadIdx.x] = p[threadIdx.x];
        __syncthreads();
    }
    int idx = blockIdx.x * 256 + threadIdx.x;
    int tot = (p ? npow : n) * 32;
    if (idx >= tot) return;
    int i = idx >> 5, c = idx & 31;
    float v = 0.f;
    if (i < n) {
        float s = 0.f;
        for (int z = 0; z < jsplit; z++) s += aggp[(long)z * APSTR + idx];
        v = (s + fixb[i] * msg[idx]) * dis[i] + bb[c];
        if (relu) v = fmaxf(v, 0.f);
        out[idx] = v;
    }
    if (p) {
        float pc = psh[c];
        float d = v * pc;
        float nq = pc * pc;
#pragma unroll
        for (int st = 16; st >= 1; st >>= 1) {
            d += __shfl_xor(d, st);
            nq += __shfl_xor(nq, st);
        }
        if (c == 0) {
            unsigned long long kk = 0ULL;
            if (i < n) {
                float sc = tanhf(d / sqrtf(nq));
                unsigned u = __float_as_uint(sc);
                u = (u & 0x80000000u) ? ~u : (u | 0x80000000u);
                kk = ((unsigned long long)u << 32) | (unsigned)(~i);
            }
            keys[i] = kk;
        }
    }
}

// level-0 msg with inline degree finalize
__global__ void msg0_kernel(const float* __restrict__ x, const float* __restrict__ Wb,
                            const int* __restrict__ rowcntD, const int* __restrict__ diagcnt,
                            float* __restrict__ dis, float* __restrict__ fixb,
                            float* __restrict__ msg, int n) {
    int idx = blockIdx.x * 256 + threadIdx.x;
    if (idx >= n * 32) return;
    int i = idx >> 5, c = idx & 31;
    float fx = diagcnt[i] > 0 ? 0.f : 2.f;
    float dg = (float)rowcntD[i] + fx;
    float di = dg > 0.f ? 1.f / sqrtf(dg) : 0.f;
    if (c == 0) { dis[i] = di; fixb[i] = fx; }
    float s = x[i * 3] * Wb[c] + x[i * 3 + 1] * Wb[32 + c] + x[i * 3 + 2] * Wb[64 + c];
    msg[idx] = s * di;
}

// final up-level msg (32->3) with fused unpool: xv = res[i] + (invp[i]>=0 ? xup[invp[i]] : 0)
__global__ void msg3up_kernel(const float* __restrict__ res, const float* __restrict__ xup,
                              const int* __restrict__ invp, const float* __restrict__ Wb,
                              const float* __restrict__ dis, float* __restrict__ msg, int n) {
    int idx = blockIdx.x * 256 + threadIdx.x;
    if (idx >= n * 3) return;
    int i = idx / 3, c = idx % 3;
    int ip = invp[i];
    float s = 0.f;
#pragma unroll
    for (int q = 0; q < 32; q++) {
        float xv = res[(long)i * 32 + q];
        if (ip >= 0) xv += xup[(long)ip * 32 + q];
        s += xv * Wb[q * 3 + c];
    }
    msg[idx] = s * dis[i];
}

// level-0 sparse agg + epilogue + level-0 pooling keys (wave-reduced)
__global__ void cscagg_epi_keys_kernel(const int* __restrict__ rowpD, const int* __restrict__ srcs,
                                       const float* __restrict__ msg, const float* __restrict__ dis,
                                       const float* __restrict__ fixb, const float* __restrict__ bb,
                                       float* __restrict__ out, int n, const float* __restrict__ p,
                                       unsigned long long* __restrict__ keys) {
    __shared__ float psh[32];
    if (threadIdx.x < 32) psh[threadIdx.x] = p[threadIdx.x];
    __syncthreads();
    int idx = blockIdx.x * 256 + threadIdx.x;
    if (idx >= n * 32) return;
    int i = idx >> 5, c = idx & 31;
    float acc = 0.f;
    int e0 = rowpD[i], e1 = rowpD[i + 1];
    for (int e = e0; e < e1; e++) acc += msg[(long)srcs[e] * 32 + c];
    float v = (acc + fixb[i] * msg[idx]) * dis[i] + bb[c];
    v = fmaxf(v, 0.f);
    out[idx] = v;
    float pc = psh[c];
    float d = v * pc;
    float nq = pc * pc;
#pragma unroll
    for (int st = 16; st >= 1; st >>= 1) {
        d += __shfl_xor(d, st);
        nq += __shfl_xor(nq, st);
    }
    if (c == 0) {
        float sc = tanhf(d / sqrtf(nq));
        unsigned u = __float_as_uint(sc);
        u = (u & 0x80000000u) ? ~u : (u | 0x80000000u);
        keys[i] = ((unsigned long long)u << 32) | (unsigned)(~i);
    }
}

// final sparse GCN epilogue + log_softmax fused, writes d_out directly
__global__ void cscagg_lsm_kernel(const int* __restrict__ rowpD, const int* __restrict__ srcs,
                                  const float* __restrict__ msg, const float* __restrict__ dis,
                                  const float* __restrict__ fixb, const float* __restrict__ bb,
                                  float* __restrict__ out, int n) {
    int i = blockIdx.x * 256 + threadIdx.x;
    if (i >= n) return;
    float a0 = 0.f, a1 = 0.f, a2 = 0.f;
    int e0 = rowpD[i], e1 = rowpD[i + 1];
    for (int e = e0; e < e1; e++) {
        const float* m = &msg[(long)srcs[e] * 3];
        a0 += m[0]; a1 += m[1]; a2 += m[2];
    }
    float di = dis[i], fx = fixb[i];
    float v0 = (a0 + fx * msg[i * 3]) * di + bb[0];
    float v1 = (a1 + fx * msg[i * 3 + 1]) * di + bb[1];
    float v2 = (a2 + fx * msg[i * 3 + 2]) * di + bb[2];
    float m = fmaxf(v0, fmaxf(v1, v2));
    float s = expf(v0 - m) + expf(v1 - m) + expf(v2 - m);
    float l = m + logf(s);
    out[i * 3] = v0 - l;
    out[i * 3 + 1] = v1 - l;
    out[i * 3 + 2] = v2 - l;
}

// rank(i)=#{j: key_j>key_i}; also emits invperm[i] = rank<k ? rank : -1 for ALL nodes.
__global__ __launch_bounds__(256) void topk_rank_kernel(const unsigned long long* __restrict__ keys,
                                                        int npow, int k, int* __restrict__ perm,
                                                        float* __restrict__ vals,
                                                        int* __restrict__ invperm) {
    __shared__ unsigned long long ks[4096];
    __shared__ int psum[256];
    const int tid = threadIdx.x;
    for (int t = tid; t < npow; t += 256) ks[t] = keys[t];
    __syncthreads();
    const int m = tid & 15;
    const int chunk = tid >> 4;
    const int myi = blockIdx.x * 16 + m;
    unsigned long long my = ks[myi];
    const int cl = npow >> 4;
    const unsigned long long* base = &ks[chunk * cl];
    int r = 0;
#pragma unroll 4
    for (int j = 0; j < cl; j++) r += (base[j] > my) ? 1 : 0;
    psum[chunk * 16 + m] = r;
    __syncthreads();
    if (tid < 16) {
        int mk_i = blockIdx.x * 16 + tid;
        unsigned long long mk = ks[mk_i];
        int rank = 0;
#pragma unroll
        for (int c = 0; c < 16; c++) rank += psum[c * 16 + tid];
        invperm[mk_i] = (rank < k) ? rank : -1;
        if (rank < k) {
            perm[rank] = (int)(~(unsigned)mk);
            unsigned u = (unsigned)(mk >> 32);
            u = (u & 0x80000000u) ? (u ^ 0x80000000u) : ~u;
            vals[rank] = __uint_as_float(u);
        }
    }
}

// ---------------- host ----------------
static void run_gcn_dense(hipStream_t st, const float* A, int n, int ld, const float* x,
                          const int* perm, const float* vals, const float* xup, const int* invp,
                          const float* Wt, const float* bt, int relu, float* out, float* degp,
                          float* aggp, float* dis, float* fixb, float* msgb, int computeDeg,
                          const float* pnext, int npow_next, unsigned long long* keys) {
    if (computeDeg) {
        dim3 gcs(ld / 256 > 0 ? ld / 256 : 1, ld / 64);
        colsum_part_kernel<<<gcs, 256, 0, st>>>(A, degp, ld);
    }
    int gm = (n * H + 255) / 256;
    msgg_kernel<<<gm, 256, 0, st>>>(x, perm, vals, xup, invp, Wt, A, ld,
                                    computeDeg ? degp : nullptr, ld / 64, dis, fixb, msgb, n);
    int jsplit = ld / 256 > 0 ? ld / 256 : 1;
    int ajc = ld / jsplit;
    dim3 ga(ld / 64, jsplit);
    aggT_kernel<<<ga, 256, 0, st>>>(A, msgb, aggp, n, ld, ajc);
    int gme = ((pnext ? npow_next : n) * H + 255) / 256;
    epi_sum_kernel<<<gme, 256, 0, st>>>(aggp, jsplit, msgb, dis, fixb, bt, out, n, relu,
                                        pnext, npow_next, keys);
}

extern "C" void kernel_launch(void* const* d_in, const int* in_sizes, int n_in,
                              void* d_out, int out_size, void* d_ws, size_t ws_size,
                              hipStream_t stream) {
    const float* x0f = (const float*)d_in[0];
    const int* eidx = (const int*)d_in[1];
    const float* W0f = (const float*)d_in[2];
    const float* b0f = (const float*)d_in[3];
    const float* Wdf = (const float*)d_in[4];
    const float* bdf = (const float*)d_in[5];
    const float* Pf = (const float*)d_in[6];
    const float* Wuf = (const float*)d_in[7];
    const float* buf2 = (const float*)d_in[8];
    const float* Wlf = (const float*)d_in[9];
    const float* blf = (const float*)d_in[10];
    const int E = in_sizes[1] / 2;

    unsigned char* w = (unsigned char*)d_ws;
    size_t off = 0;
    auto alloc = [&](size_t bytes) -> void* {
        void* p = w + off;
        off += (bytes + 255) & ~(size_t)255;
        return p;
    };
    int* rowcnt = (int*)alloc(N0 * 4);
    int* rowcntD = (int*)alloc(N0 * 4);
    int* diagcnt = (int*)alloc(N0 * 4);
    int* rowp = (int*)alloc((N0 + 1) * 4);
    int* rowpD = (int*)alloc((N0 + 1) * 4);
    int* cursor = (int*)alloc(N0 * 4);
    int* cursorD = (int*)alloc(N0 * 4);
    int* cols = (int*)alloc((size_t)EMAX * 4);
    int* srcs = (int*)alloc((size_t)EMAX * 4);
    float* dis0 = (float*)alloc(N0 * 4);
    float* fixb0 = (float*)alloc(N0 * 4);
    unsigned long long* keys = (unsigned long long*)alloc((size_t)N0 * 8);
    float* A1 = (float*)alloc((size_t)2048 * 2048 * 4);
    float* A2 = (float*)alloc((size_t)1024 * 1024 * 4);
    float* A3 = (float*)alloc((size_t)512 * 512 * 4);
    float* A4 = (float*)alloc((size_t)256 * 256 * 4);
    float* Gr = (float*)alloc((size_t)1024 * 2048 * 4);
    float* Gc = (float*)alloc((size_t)2048 * 1024 * 4);
    unsigned short* Grb = (unsigned short*)alloc((size_t)1024 * 2048 * 2);
    unsigned short* GcTb = (unsigned short*)alloc((size_t)1024 * 2048 * 2);
    float* Cpart = (float*)alloc((size_t)8 * 512 * 512 * 4);
    float* degp = (float*)alloc((size_t)32 * 2048 * 4);
    float* aggp = (float*)alloc((size_t)8 * APSTR * 4);
    float* xs0 = (float*)alloc((size_t)N0 * H * 4);
    float* xs1 = (float*)alloc((size_t)2000 * H * 4);
    float* xs2 = (float*)alloc((size_t)1000 * H * 4);
    float* xs3 = (float*)alloc((size_t)500 * H * 4);
    float* xtB = (float*)alloc((size_t)N0 * H * 4);
    float* xtC = (float*)alloc((size_t)N0 * H * 4);
    float* msgb = (float*)alloc((size_t)N0 * H * 4);
    float* disL = (float*)alloc((size_t)4 * N0 * 4);    // per-level cached dis (adjacency 1..4)
    float* fixbL = (float*)alloc((size_t)4 * N0 * 4);
    int* invpermL = (int*)alloc((size_t)4 * N0 * 4);    // per-level node->rank (or -1)
    const int ksz[4] = {2000, 1000, 500, 250};
    int* perm[4];
    float* vals[4];
    for (int i = 0; i < 4; i++) perm[i] = (int*)alloc((size_t)ksz[i] * 4);
    for (int i = 0; i < 4; i++) vals[i] = (float*)alloc((size_t)ksz[i] * 4);

    if (off > ws_size) {
        fill_sentinel_kernel<<<(out_size + 255) / 256, 256, 0, stream>>>((float*)d_out, out_size);
        return;
    }

    const int nlvl[5] = {N0, 2000, 1000, 500, 250};
    const int ldl[5] = {N0, 2048, 1024, 512, 256};
    const int npw[4] = {4096, 2048, 1024, 512};
    float* Afp[5] = {nullptr, A1, A2, A3, A4};
    float* xsb[4] = {xs0, xs1, xs2, xs3};

    // ---- CSR build + level-0 stats ----
    hipMemsetAsync(rowcnt, 0, (size_t)N0 * 3 * 4, stream);
    build_stats_kernel<<<(E + 255) / 256, 256, 0, stream>>>(eidx, E, rowcnt, rowcntD, diagcnt);
    scan2_kernel<<<1, 1024, 0, stream>>>(rowcnt, rowp, cursor, rowcntD, rowpD, cursorD);
    fill_csr_kernel<<<(E + 255) / 256, 256, 0, stream>>>(eidx, E, cursor, cols, cursorD, srcs);

    // ---- GCN level 0 (sparse, 3->32, relu) + level-0 pooling keys ----
    msg0_kernel<<<(N0 * H + 255) / 256, 256, 0, stream>>>(x0f, W0f, rowcntD, diagcnt, dis0, fixb0,
                                                          msgb, N0);
    cscagg_epi_keys_kernel<<<(N0 * H + 255) / 256, 256, 0, stream>>>(rowpD, srcs, msgb, dis0, fixb0,
                                                                     b0f, xs0, N0, Pf, keys);
    float* xcur = xs0;

    // ---- down path ----
    for (int i = 0; i < 4; ++i) {
        int kk = ksz[i], ldn = ldl[i + 1];
        topk_rank_kernel<<<npw[i] / 16, 256, 0, stream>>>(keys, npw[i], kk, perm[i], vals[i],
                                                          invpermL + i * N0);
        if (i == 0) {
            aug0_kernel<<<ldn, 256, 0, stream>>>(rowp, cols, perm[0], invpermL, kk, ldn, A1);
        } else if (i == 1) {
            int ldM = ldl[i];
            dim3 gr((ldM + 255) / 256, ldn);
            gather_rows_bf16_kernel<<<gr, 256, 0, stream>>>(Afp[i], ldM, perm[i], kk, Grb);
            dim3 gt(ldn / 32, ldM / 32);
            gather_colsT_bf16_kernel<<<gt, dim3(32, 8), 0, stream>>>(Afp[i], ldM, perm[i], kk, GcTb);
            hipMemsetAsync(Afp[i + 1], 0, (size_t)ldn * ldn * 4, stream);
            int ksplit = 4;
            int kchunk = ldM / ksplit;
            dim3 gg(ldn / 64, ldn / 64, ksplit);
            mfma_aug_kernel<<<gg, 256, 0, stream>>>(Grb, GcTb, Afp[i + 1], ldM, ldn, kchunk);
        } else {
            int ldM = ldl[i];
            dim3 gr((ldM + 255) / 256, ldn);
            gather_rows_kernel<<<gr, 256, 0, stream>>>(Afp[i], ldM, perm[i], kk, Gr);
            dim3 gc((ldn + 255) / 256, ldM);
            gather_cols_kernel<<<gc, 256, 0, stream>>>(Afp[i], ldM, perm[i], kk, Gc, ldn);
            int ksplit = 8;
            int kchunk = ldM / ksplit;
            dim3 gg(ldn / 64, ldn / 64, ksplit);
            gemm64_kernel<<<gg, 256, 0, stream>>>(Gr, Gc, Cpart, ldM, ldn, kchunk);
            long tot = (long)ldn * ldn;
            reduce_part_kernel<<<(tot + 255) / 256, 256, 0, stream>>>(Cpart, Afp[i + 1], ldn, ksplit);
        }
        float* outx = (i < 3) ? xsb[i + 1] : xtB;
        const float* pnext = (i < 3) ? (Pf + (i + 1) * H) : nullptr;
        int npow_next = (i < 3) ? npw[i + 1] : 0;
        run_gcn_dense(stream, Afp[i + 1], kk, ldn, xcur, perm[i], vals[i], nullptr, nullptr,
                      Wdf + i * (H * H), bdf + i * H, 1, outx, degp, aggp, disL + i * N0,
                      fixbL + i * N0, msgb, 1, pnext, npow_next, keys);
        xcur = outx;
    }

    // ---- up path (dis/fixb cached; unpool fused into msg via invperm) ----
    for (int i = 0; i < 4; ++i) {
        int j = 3 - i;
        int nj = nlvl[j];
        if (i < 3) {
            float* outx = (xcur == xtB) ? xtC : xtB;
            run_gcn_dense(stream, Afp[j], nj, ldl[j], xsb[j], nullptr, nullptr, xcur,
                          invpermL + j * N0, Wuf + i * (H * H), buf2 + i * H, 1, outx, degp, aggp,
                          disL + (j - 1) * N0, fixbL + (j - 1) * N0, msgb, 0, nullptr, 0, nullptr);
            xcur = outx;
        } else {
            msg3up_kernel<<<(N0 * 3 + 255) / 256, 256, 0, stream>>>(xs0, xcur, invpermL, Wlf, dis0,
                                                                    msgb, N0);
            cscagg_lsm_kernel<<<(N0 + 255) / 256, 256, 0, stream>>>(rowpD, srcs, msgb, dis0, fixb0,
                                                                    blf, (float*)d_out, N0);
        }
    }
}